// Round 1
// baseline (1012.453 us; speedup 1.0000x reference)
//
#include <hip/hip_runtime.h>

// LIF constants (match reference)
#define KOEFF 0.951229424500714f

typedef unsigned short u16;
typedef __attribute__((ext_vector_type(8))) short short8;   // 8 bf16 = 4 VGPRs (MFMA A/B frag)
typedef __attribute__((ext_vector_type(4))) float f32x4;    // MFMA C/D frag

__device__ __forceinline__ u16 f2bf(float f) {
  // round-to-nearest-even fp32 -> bf16 (no NaN handling needed: inputs are finite)
  unsigned int v = __float_as_uint(f);
  unsigned int r = (v + 0x7FFFu + ((v >> 16) & 1u)) >> 16;
  return (u16)r;
}
__device__ __forceinline__ float bf2f(u16 u) {
  return __uint_as_float(((unsigned int)u) << 16);
}

// ---------------------------------------------------------------------------
// Kernel 1: X [64][512 j][512 t] fp32 -> XT16 [64][512 t][512 j] bf16 (tiled transpose)
// ---------------------------------------------------------------------------
__global__ __launch_bounds__(256) void k_xt(const float* __restrict__ X, u16* __restrict__ XT) {
  __shared__ float tile[64][65];
  const int b  = blockIdx.z;
  const int j0 = blockIdx.x * 64;
  const int t0 = blockIdx.y * 64;
  const float* src = X + ((size_t)b * 512 + j0) * 512 + t0;
  for (int e = threadIdx.x; e < 64 * 16; e += 256) {
    int r = e >> 4, c = e & 15;
    float4 v = *(const float4*)(src + (size_t)r * 512 + c * 4);
    tile[r][c * 4 + 0] = v.x; tile[r][c * 4 + 1] = v.y;
    tile[r][c * 4 + 2] = v.z; tile[r][c * 4 + 3] = v.w;
  }
  __syncthreads();
  u16* dst = XT + ((size_t)b * 512 + t0) * 512 + j0;
  for (int e = threadIdx.x; e < 64 * 16; e += 256) {
    int tr = e >> 4, c = e & 15;
    ushort4 o;
    o.x = f2bf(tile[c * 4 + 0][tr]); o.y = f2bf(tile[c * 4 + 1][tr]);
    o.z = f2bf(tile[c * 4 + 2][tr]); o.w = f2bf(tile[c * 4 + 3][tr]);
    *(ushort4*)(dst + (size_t)tr * 512 + c * 4) = o;
  }
}

// ---------------------------------------------------------------------------
// Kernel 2: W rows 512..2047, cols 0..511 -> bf16 hi/lo split [1536][512]
// ---------------------------------------------------------------------------
__global__ __launch_bounds__(256) void k_wsplit(const float* __restrict__ W,
                                                u16* __restrict__ Whi, u16* __restrict__ Wlo) {
  int p = blockIdx.x * 256 + threadIdx.x;
  if (p >= 1536 * 512) return;
  int i = p >> 9, j = p & 511;
  float w = W[(size_t)(512 + i) * 2048 + j];
  u16 hi = f2bf(w);
  Whi[p] = hi;
  Wlo[p] = f2bf(w - bf2f(hi));
}

// ---------------------------------------------------------------------------
// Kernel 3: WT2[j'][i'] = W[512+i'][512+j']  (recurrent block, transposed, fp32)
// spike at global neuron 512+j' adds row WT2[j'] to all states (coalesced)
// ---------------------------------------------------------------------------
__global__ __launch_bounds__(256) void k_wt2(const float* __restrict__ W, float* __restrict__ WT2) {
  __shared__ float tile[64][65];
  const int i0 = blockIdx.x * 64;   // 24 tiles over i'
  const int j0 = blockIdx.y * 64;   // 24 tiles over j'
  const float* src = W + (size_t)(512 + i0) * 2048 + 512 + j0;
  for (int e = threadIdx.x; e < 64 * 16; e += 256) {
    int r = e >> 4, c = e & 15;
    float4 v = *(const float4*)(src + (size_t)r * 2048 + c * 4);
    tile[r][c * 4 + 0] = v.x; tile[r][c * 4 + 1] = v.y;
    tile[r][c * 4 + 2] = v.z; tile[r][c * 4 + 3] = v.w;
  }
  __syncthreads();
  float* dst = WT2 + (size_t)j0 * 1536 + i0;
  for (int e = threadIdx.x; e < 64 * 16; e += 256) {
    int jr = e >> 4, c = e & 15;
    float4 o;
    o.x = tile[c * 4 + 0][jr]; o.y = tile[c * 4 + 1][jr];
    o.z = tile[c * 4 + 2][jr]; o.w = tile[c * 4 + 3][jr];
    *(float4*)(dst + (size_t)jr * 1536 + c * 4) = o;
  }
}

// ---------------------------------------------------------------------------
// Kernel 4: U[b][t][i'] = sum_j (Whi+Wlo)[i'][j] * XT16[b][t][j]   (fp32 accum MFMA)
// 128x128 tile, BK=64, 4 waves each 64x64, m97-style global_load_lds staging.
// ---------------------------------------------------------------------------
__global__ __launch_bounds__(256) void k_gemm(const u16* __restrict__ Ahi, const u16* __restrict__ Alo,
                                              const u16* __restrict__ Bx, float* __restrict__ U) {
  __shared__ u16 lAhi[128 * 64];
  __shared__ u16 lAlo[128 * 64];
  __shared__ u16 lB[128 * 64];
  const int b    = blockIdx.y;
  const int mt   = blockIdx.x >> 2;
  const int nt   = blockIdx.x & 3;
  const int tid  = threadIdx.x;
  const int wv   = tid >> 6;
  const int lane = tid & 63;
  const int wr   = wv >> 1, wc = wv & 1;

  f32x4 acc[4][4];
#pragma unroll
  for (int mi = 0; mi < 4; ++mi)
#pragma unroll
    for (int ni = 0; ni < 4; ++ni) acc[mi][ni] = (f32x4)0.0f;

  const u16* gAh = Ahi + (size_t)mt * 128 * 512;
  const u16* gAl = Alo + (size_t)mt * 128 * 512;
  const u16* gB  = Bx + ((size_t)b * 512 + nt * 128) * 512;

  for (int k0 = 0; k0 < 512; k0 += 64) {
#pragma unroll
    for (int it = 0; it < 4; ++it) {
      int byteoff = wv * 4096 + it * 1024 + lane * 16;  // within 16KB tile
      int row  = byteoff >> 7;        // 128B per row (64 bf16 of k)
      int ksub = ((byteoff >> 4) & 7) * 8;
      int ldsoff = wv * 2048 + it * 512;  // u16 elements, wave-uniform
      __builtin_amdgcn_global_load_lds(
          (const __attribute__((address_space(1))) void*)(gAh + (size_t)row * 512 + k0 + ksub),
          (__attribute__((address_space(3))) void*)(lAhi + ldsoff), 16, 0, 0);
      __builtin_amdgcn_global_load_lds(
          (const __attribute__((address_space(1))) void*)(gAl + (size_t)row * 512 + k0 + ksub),
          (__attribute__((address_space(3))) void*)(lAlo + ldsoff), 16, 0, 0);
      __builtin_amdgcn_global_load_lds(
          (const __attribute__((address_space(1))) void*)(gB + (size_t)row * 512 + k0 + ksub),
          (__attribute__((address_space(3))) void*)(lB + ldsoff), 16, 0, 0);
    }
    __syncthreads();
#pragma unroll
    for (int kk = 0; kk < 2; ++kk) {
      short8 ah[4], al[4], bb[4];
      const int krow = kk * 32 + (lane >> 4) * 8;
#pragma unroll
      for (int mi = 0; mi < 4; ++mi) {
        int m = wr * 64 + mi * 16 + (lane & 15);
        ah[mi] = *(const short8*)&lAhi[m * 64 + krow];
        al[mi] = *(const short8*)&lAlo[m * 64 + krow];
      }
#pragma unroll
      for (int ni = 0; ni < 4; ++ni) {
        int n = wc * 64 + ni * 16 + (lane & 15);
        bb[ni] = *(const short8*)&lB[n * 64 + krow];
      }
#pragma unroll
      for (int mi = 0; mi < 4; ++mi)
#pragma unroll
        for (int ni = 0; ni < 4; ++ni) {
          acc[mi][ni] = __builtin_amdgcn_mfma_f32_16x16x32_bf16(ah[mi], bb[ni], acc[mi][ni], 0, 0, 0);
          acc[mi][ni] = __builtin_amdgcn_mfma_f32_16x16x32_bf16(al[mi], bb[ni], acc[mi][ni], 0, 0, 0);
        }
    }
    __syncthreads();
  }
  // epilogue: D layout col=lane&15 (n=t), row=(lane>>4)*4+q (m=i) [m89-verified]
#pragma unroll
  for (int mi = 0; mi < 4; ++mi) {
    int ib = mt * 128 + wr * 64 + mi * 16 + ((lane >> 4) << 2);
#pragma unroll
    for (int ni = 0; ni < 4; ++ni) {
      int t = nt * 128 + wc * 64 + ni * 16 + (lane & 15);
      *(f32x4*)(U + ((size_t)b * 512 + t) * 1536 + ib) = acc[mi][ni];
    }
  }
}

// ---------------------------------------------------------------------------
// Kernel 5: exact sequential scan. One block per batch, 768 threads, 2 neurons
// each (i' = 2*tid, 2*tid+1; global neuron 512+i'). Spike exchange via
// per-wave ballots in LDS. Handles any spike pattern exactly.
// ---------------------------------------------------------------------------
__global__ __launch_bounds__(768) void k_scan(const float* __restrict__ U, const float* __restrict__ WT2,
                                              float* __restrict__ out) {
  const int b = blockIdx.x, tid = threadIdx.x;
  const int wv = tid >> 6, lane = tid & 63;
  __shared__ unsigned long long spk[24];
  for (int w = tid; w < 24; w += 768) spk[w] = 0ULL;
  __syncthreads();
  float s0 = 0.f, s1 = 0.f, r0 = 0.f, r1 = 0.f;
  const int i0 = 2 * tid;
  const float* ub = U + (size_t)b * 512 * 1536 + i0;
  float2 u = *(const float2*)ub;
  for (int t = 0; t < 512; ++t) {
    float2 unext = u;
    if (t < 511) unext = *(const float2*)(ub + (size_t)(t + 1) * 1536);
    float a0 = fmaf(s0, KOEFF, u.x);
    float a1 = fmaf(s1, KOEFF, u.y);
    // recurrent contributions from previous step's spikes (rare)
    for (int wd = 0; wd < 24; ++wd) {
      unsigned long long m = spk[wd];
      while (m) {
        int bit = __ffsll(m) - 1;
        m &= m - 1;
        int jp = ((wd >> 1) << 7) + (bit << 1) + (wd & 1);
        float2 rv = *(const float2*)(WT2 + (size_t)jp * 1536 + i0);
        a0 += rv.x; a1 += rv.y;
      }
    }
    if (r0 > 0.f) a0 = 0.f;
    if (r1 > 0.f) a1 = 0.f;
    bool sp0 = a0 >= 1.0f, sp1 = a1 >= 1.0f;
    r0 -= 1.f; r1 -= 1.f;
    if (sp0) r0 = 2.f;
    if (sp1) r1 = 2.f;
    if (a0 < -1.f) a0 = -1.f;
    if (a1 < -1.f) a1 = -1.f;
    s0 = a0; s1 = a1;
    if (i0 >= 1280) {  // global neurons 1792.. -> output
      float* o = out + ((size_t)b * 256 + (i0 - 1280)) * 512 + t;
      o[0]   = sp0 ? 1.f : 0.f;
      o[512] = sp1 ? 1.f : 0.f;
    }
    __syncthreads();  // all reads of spk done
    unsigned long long b0 = __ballot(sp0);
    unsigned long long b1 = __ballot(sp1);
    if (lane == 0) { spk[2 * wv] = b0; spk[2 * wv + 1] = b1; }
    __syncthreads();  // lists ready for next step
    u = unext;
  }
}

// ---------------------------------------------------------------------------
// Fallback: WTF[j][i'] = W[512+i'][j] for all j in [0,2048)  (12.6 MB)
// ---------------------------------------------------------------------------
__global__ __launch_bounds__(256) void k_wtf(const float* __restrict__ W, float* __restrict__ WTF) {
  __shared__ float tile[64][65];
  const int i0 = blockIdx.x * 64;   // 24 tiles over i'
  const int j0 = blockIdx.y * 64;   // 32 tiles over j
  const float* src = W + (size_t)(512 + i0) * 2048 + j0;
  for (int e = threadIdx.x; e < 64 * 16; e += 256) {
    int r = e >> 4, c = e & 15;
    float4 v = *(const float4*)(src + (size_t)r * 2048 + c * 4);
    tile[r][c * 4 + 0] = v.x; tile[r][c * 4 + 1] = v.y;
    tile[r][c * 4 + 2] = v.z; tile[r][c * 4 + 3] = v.w;
  }
  __syncthreads();
  float* dst = WTF + (size_t)j0 * 1536 + i0;
  for (int e = threadIdx.x; e < 64 * 16; e += 256) {
    int jr = e >> 4, c = e & 15;
    float4 o;
    o.x = tile[c * 4 + 0][jr]; o.y = tile[c * 4 + 1][jr];
    o.z = tile[c * 4 + 2][jr]; o.w = tile[c * 4 + 3][jr];
    *(float4*)(dst + (size_t)jr * 1536 + c * 4) = o;
  }
}

// ---------------------------------------------------------------------------
// Fallback exact simulator (only used when ws_size is too small for fast path)
// 64 blocks (one per batch) x 256 threads, 6 neurons/thread.
// ---------------------------------------------------------------------------
__global__ __launch_bounds__(256) void k_exact(const float* __restrict__ X, const float* __restrict__ W,
                                               const float* __restrict__ WTF, int use_wt,
                                               float* __restrict__ out) {
  const int b = blockIdx.x, tid = threadIdx.x;
  const int wv = tid >> 6, lane = tid & 63;
  float st[6], rf[6];
#pragma unroll
  for (int r = 0; r < 6; ++r) { st[r] = 0.f; rf[r] = 0.f; }
  __shared__ unsigned int mask[64];  // bits for j = 0..2047 (inputs + prev spikes)
  for (int w = tid; w < 64; w += 256) mask[w] = 0u;
  __syncthreads();
  for (int t = 0; t < 512; ++t) {
    {
      float x = X[((size_t)b * 512 + tid) * 512 + t];
      unsigned long long bl = __ballot(x > 0.5f);
      if (lane == 0) { mask[2 * wv] = (unsigned int)bl; mask[2 * wv + 1] = (unsigned int)(bl >> 32); }
      x = X[((size_t)b * 512 + 256 + tid) * 512 + t];
      bl = __ballot(x > 0.5f);
      if (lane == 0) { mask[8 + 2 * wv] = (unsigned int)bl; mask[9 + 2 * wv] = (unsigned int)(bl >> 32); }
    }
    __syncthreads();
    float add[6] = {0.f, 0.f, 0.f, 0.f, 0.f, 0.f};
    for (int wd = 0; wd < 64; ++wd) {
      unsigned int m = mask[wd];
      while (m) {
        int bitp = __ffs(m) - 1;
        m &= m - 1;
        int j = wd * 32 + bitp;
        if (use_wt) {
          const float* row = WTF + (size_t)j * 1536;
#pragma unroll
          for (int r = 0; r < 6; ++r) add[r] += row[tid + 256 * r];
        } else {
#pragma unroll
          for (int r = 0; r < 6; ++r) add[r] += W[(size_t)(512 + tid + 256 * r) * 2048 + j];
        }
      }
    }
    bool sp[6];
#pragma unroll
    for (int r = 0; r < 6; ++r) {
      float a = fmaf(st[r], KOEFF, add[r]);
      if (rf[r] > 0.f) a = 0.f;
      sp[r] = a >= 1.0f;
      rf[r] -= 1.f;
      if (sp[r]) rf[r] = 2.f;
      if (a < -1.f) a = -1.f;
      st[r] = a;
      int gi = 512 + tid + 256 * r;
      if (gi >= 1792) out[((size_t)b * 256 + (gi - 1792)) * 512 + t] = sp[r] ? 1.f : 0.f;
    }
    __syncthreads();
#pragma unroll
    for (int r = 0; r < 6; ++r) {
      unsigned long long bl = __ballot(sp[r]);
      if (lane == 0) {
        mask[16 + 8 * r + 2 * wv] = (unsigned int)bl;
        mask[17 + 8 * r + 2 * wv] = (unsigned int)(bl >> 32);
      }
    }
    __syncthreads();
  }
}

// ---------------------------------------------------------------------------
extern "C" void kernel_launch(void* const* d_in, const int* in_sizes, int n_in,
                              void* d_out, int out_size, void* d_ws, size_t ws_size,
                              hipStream_t stream) {
  const float* X = (const float*)d_in[0];   // [64][512][512]
  const float* W = (const float*)d_in[1];   // [2048][2048]
  float* out = (float*)d_out;               // [64][256][512]
  char* ws = (char*)d_ws;

  const size_t SZ_XT  = 64ull * 512 * 512 * 2;     // 33,554,432
  const size_t SZ_WH  = 1536ull * 512 * 2;         //  1,572,864
  const size_t SZ_WT2 = 1536ull * 1536 * 4;        //  9,437,184
  const size_t SZ_U   = 64ull * 512 * 1536 * 4;    // 201,326,592
  const size_t NEED_FULL = SZ_XT + 2 * SZ_WH + SZ_WT2 + SZ_U;  // ~236 MiB
  const size_t NEED_MID  = 2048ull * 1536 * 4;                 // ~12.6 MiB

  if (ws_size >= NEED_FULL) {
    u16*   XT  = (u16*)ws;
    u16*   Whi = (u16*)(ws + SZ_XT);
    u16*   Wlo = (u16*)(ws + SZ_XT + SZ_WH);
    float* WT2 = (float*)(ws + SZ_XT + 2 * SZ_WH);
    float* U   = (float*)(ws + SZ_XT + 2 * SZ_WH + SZ_WT2);
    k_xt<<<dim3(8, 8, 64), 256, 0, stream>>>(X, XT);
    k_wsplit<<<3072, 256, 0, stream>>>(W, Whi, Wlo);
    k_wt2<<<dim3(24, 24), 256, 0, stream>>>(W, WT2);
    k_gemm<<<dim3(48, 64), 256, 0, stream>>>(Whi, Wlo, XT, U);
    k_scan<<<64, 768, 0, stream>>>(U, WT2, out);
  } else if (ws_size >= NEED_MID) {
    float* WTF = (float*)ws;
    k_wtf<<<dim3(24, 32), 256, 0, stream>>>(W, WTF);
    k_exact<<<64, 256, 0, stream>>>(X, W, WTF, 1, out);
  } else {
    k_exact<<<64, 256, 0, stream>>>(X, W, nullptr, 0, out);
  }
}

// Round 2
// 463.902 us; speedup vs baseline: 2.1825x; 2.1825x over previous
//
#include <hip/hip_runtime.h>

// LIF constants (match reference)
#define KOEFF 0.951229424500714f

typedef unsigned short u16;
typedef __attribute__((ext_vector_type(8))) short short8;   // 8 bf16 = 4 VGPRs (MFMA A/B frag)
typedef __attribute__((ext_vector_type(4))) float f32x4;    // MFMA C/D frag

__device__ __forceinline__ u16 f2bf(float f) {
  unsigned int v = __float_as_uint(f);
  unsigned int r = (v + 0x7FFFu + ((v >> 16) & 1u)) >> 16;
  return (u16)r;
}
__device__ __forceinline__ float bf2f(u16 u) {
  return __uint_as_float(((unsigned int)u) << 16);
}

// ---------------------------------------------------------------------------
// Kernel 1: X [64][512 j][512 t] fp32 -> XT16 [64][512 t][512 j] bf16
// ---------------------------------------------------------------------------
__global__ __launch_bounds__(256) void k_xt(const float* __restrict__ X, u16* __restrict__ XT) {
  __shared__ float tile[64][65];
  const int b  = blockIdx.z;
  const int j0 = blockIdx.x * 64;
  const int t0 = blockIdx.y * 64;
  const float* src = X + ((size_t)b * 512 + j0) * 512 + t0;
  for (int e = threadIdx.x; e < 64 * 16; e += 256) {
    int r = e >> 4, c = e & 15;
    float4 v = *(const float4*)(src + (size_t)r * 512 + c * 4);
    tile[r][c * 4 + 0] = v.x; tile[r][c * 4 + 1] = v.y;
    tile[r][c * 4 + 2] = v.z; tile[r][c * 4 + 3] = v.w;
  }
  __syncthreads();
  u16* dst = XT + ((size_t)b * 512 + t0) * 512 + j0;
  for (int e = threadIdx.x; e < 64 * 16; e += 256) {
    int tr = e >> 4, c = e & 15;
    ushort4 o;
    o.x = f2bf(tile[c * 4 + 0][tr]); o.y = f2bf(tile[c * 4 + 1][tr]);
    o.z = f2bf(tile[c * 4 + 2][tr]); o.w = f2bf(tile[c * 4 + 3][tr]);
    *(ushort4*)(dst + (size_t)tr * 512 + c * 4) = o;
  }
}

// ---------------------------------------------------------------------------
// Kernel 2: W rows 512..2047, cols 0..511 -> bf16 hi/lo split [1536][512]
// Also zeroes the 64 per-batch spike flags (block 0).
// ---------------------------------------------------------------------------
__global__ __launch_bounds__(256) void k_wsplit(const float* __restrict__ W,
                                                u16* __restrict__ Whi, u16* __restrict__ Wlo,
                                                int* __restrict__ flags) {
  if (blockIdx.x == 0 && threadIdx.x < 64) flags[threadIdx.x] = 0;
  int p = blockIdx.x * 256 + threadIdx.x;
  if (p >= 1536 * 512) return;
  int i = p >> 9, j = p & 511;
  float w = W[(size_t)(512 + i) * 2048 + j];
  u16 hi = f2bf(w);
  Whi[p] = hi;
  Wlo[p] = f2bf(w - bf2f(hi));
}

// ---------------------------------------------------------------------------
// Kernel 3: WT2[j'][i'] = W[512+i'][512+j']  (recurrent block, transposed)
// ---------------------------------------------------------------------------
__global__ __launch_bounds__(256) void k_wt2(const float* __restrict__ W, float* __restrict__ WT2) {
  __shared__ float tile[64][65];
  const int i0 = blockIdx.x * 64;
  const int j0 = blockIdx.y * 64;
  const float* src = W + (size_t)(512 + i0) * 2048 + 512 + j0;
  for (int e = threadIdx.x; e < 64 * 16; e += 256) {
    int r = e >> 4, c = e & 15;
    float4 v = *(const float4*)(src + (size_t)r * 2048 + c * 4);
    tile[r][c * 4 + 0] = v.x; tile[r][c * 4 + 1] = v.y;
    tile[r][c * 4 + 2] = v.z; tile[r][c * 4 + 3] = v.w;
  }
  __syncthreads();
  float* dst = WT2 + (size_t)j0 * 1536 + i0;
  for (int e = threadIdx.x; e < 64 * 16; e += 256) {
    int jr = e >> 4, c = e & 15;
    float4 o;
    o.x = tile[c * 4 + 0][jr]; o.y = tile[c * 4 + 1][jr];
    o.z = tile[c * 4 + 2][jr]; o.w = tile[c * 4 + 3][jr];
    *(float4*)(dst + (size_t)jr * 1536 + c * 4) = o;
  }
}

// ---------------------------------------------------------------------------
// Kernel 4: U[b][t][i'] = sum_j (Whi+Wlo)[i'][j] * XT16[b][t][j]  (fp32 MFMA)
// ---------------------------------------------------------------------------
__global__ __launch_bounds__(256) void k_gemm(const u16* __restrict__ Ahi, const u16* __restrict__ Alo,
                                              const u16* __restrict__ Bx, float* __restrict__ U) {
  __shared__ u16 lAhi[128 * 64];
  __shared__ u16 lAlo[128 * 64];
  __shared__ u16 lB[128 * 64];
  const int b    = blockIdx.y;
  const int mt   = blockIdx.x >> 2;
  const int nt   = blockIdx.x & 3;
  const int tid  = threadIdx.x;
  const int wv   = tid >> 6;
  const int lane = tid & 63;
  const int wr   = wv >> 1, wc = wv & 1;

  f32x4 acc[4][4];
#pragma unroll
  for (int mi = 0; mi < 4; ++mi)
#pragma unroll
    for (int ni = 0; ni < 4; ++ni) acc[mi][ni] = (f32x4)0.0f;

  const u16* gAh = Ahi + (size_t)mt * 128 * 512;
  const u16* gAl = Alo + (size_t)mt * 128 * 512;
  const u16* gB  = Bx + ((size_t)b * 512 + nt * 128) * 512;

  for (int k0 = 0; k0 < 512; k0 += 64) {
#pragma unroll
    for (int it = 0; it < 4; ++it) {
      int byteoff = wv * 4096 + it * 1024 + lane * 16;
      int row  = byteoff >> 7;
      int ksub = ((byteoff >> 4) & 7) * 8;
      int ldsoff = wv * 2048 + it * 512;
      __builtin_amdgcn_global_load_lds(
          (const __attribute__((address_space(1))) void*)(gAh + (size_t)row * 512 + k0 + ksub),
          (__attribute__((address_space(3))) void*)(lAhi + ldsoff), 16, 0, 0);
      __builtin_amdgcn_global_load_lds(
          (const __attribute__((address_space(1))) void*)(gAl + (size_t)row * 512 + k0 + ksub),
          (__attribute__((address_space(3))) void*)(lAlo + ldsoff), 16, 0, 0);
      __builtin_amdgcn_global_load_lds(
          (const __attribute__((address_space(1))) void*)(gB + (size_t)row * 512 + k0 + ksub),
          (__attribute__((address_space(3))) void*)(lB + ldsoff), 16, 0, 0);
    }
    __syncthreads();
#pragma unroll
    for (int kk = 0; kk < 2; ++kk) {
      short8 ah[4], al[4], bb[4];
      const int krow = kk * 32 + (lane >> 4) * 8;
#pragma unroll
      for (int mi = 0; mi < 4; ++mi) {
        int m = wr * 64 + mi * 16 + (lane & 15);
        ah[mi] = *(const short8*)&lAhi[m * 64 + krow];
        al[mi] = *(const short8*)&lAlo[m * 64 + krow];
      }
#pragma unroll
      for (int ni = 0; ni < 4; ++ni) {
        int n = wc * 64 + ni * 16 + (lane & 15);
        bb[ni] = *(const short8*)&lB[n * 64 + krow];
      }
#pragma unroll
      for (int mi = 0; mi < 4; ++mi)
#pragma unroll
        for (int ni = 0; ni < 4; ++ni) {
          acc[mi][ni] = __builtin_amdgcn_mfma_f32_16x16x32_bf16(ah[mi], bb[ni], acc[mi][ni], 0, 0, 0);
          acc[mi][ni] = __builtin_amdgcn_mfma_f32_16x16x32_bf16(al[mi], bb[ni], acc[mi][ni], 0, 0, 0);
        }
    }
    __syncthreads();
  }
#pragma unroll
  for (int mi = 0; mi < 4; ++mi) {
    int ib = mt * 128 + wr * 64 + mi * 16 + ((lane >> 4) << 2);
#pragma unroll
    for (int ni = 0; ni < 4; ++ni) {
      int t = nt * 128 + wc * 64 + ni * 16 + (lane & 15);
      *(f32x4*)(U + ((size_t)b * 512 + t) * 1536 + ib) = acc[mi][ni];
    }
  }
}

// ---------------------------------------------------------------------------
// Kernel 5 (pass A): speculative no-recurrence scan. One thread per (b, i').
// Exact whenever the batch produces no spikes under no-recurrence dynamics
// (which implies exact dynamics are identical). Flags batches with any spike.
// Prefetch depth 8, no barriers, no LDS.
// ---------------------------------------------------------------------------
__global__ __launch_bounds__(256) void k_lin(const float* __restrict__ U,
                                             float* __restrict__ out,
                                             int* __restrict__ flags) {
  const int g = blockIdx.x * 256 + threadIdx.x;   // 384 blocks -> g < 98304
  const int b = g / 1536;
  const int i = g - b * 1536;
  const float* up = U + (size_t)b * 512 * 1536 + i;
  const bool wr = (i >= 1280);
  float* op = out + ((size_t)b * 256 + (i - 1280)) * 512;   // valid only if wr

  float s = 0.f, r = 0.f;
  bool any = false;
  float buf[8];
#pragma unroll
  for (int j = 0; j < 8; ++j) buf[j] = up[(size_t)j * 1536];

  for (int t0 = 0; t0 < 512; t0 += 8) {
    float spv[8];
#pragma unroll
    for (int j = 0; j < 8; ++j) {
      float u = buf[j];
      if (t0 + 8 < 512) buf[j] = up[(size_t)(t0 + 8 + j) * 1536];  // prefetch next 8
      s = fmaf(s, KOEFF, u);
      if (r > 0.f) s = 0.f;
      bool sp = s >= 1.0f;
      r -= 1.f;
      if (sp) { r = 2.f; any = true; }
      if (s < -1.f) s = -1.f;
      spv[j] = sp ? 1.f : 0.f;
    }
    if (wr) {
      float4 o0 = make_float4(spv[0], spv[1], spv[2], spv[3]);
      float4 o1 = make_float4(spv[4], spv[5], spv[6], spv[7]);
      *(float4*)(op + t0)     = o0;
      *(float4*)(op + t0 + 4) = o1;
    }
  }
  if (any) atomicOr(&flags[b], 1);
}

// ---------------------------------------------------------------------------
// Kernel 6 (pass B): exact sequential scan, gated per batch on spike flag.
// Expected: immediate exit for all batches. Correctness backstop.
// ---------------------------------------------------------------------------
__global__ __launch_bounds__(768) void k_fix(const float* __restrict__ U, const float* __restrict__ WT2,
                                             const int* __restrict__ flags, float* __restrict__ out) {
  const int b = blockIdx.x;
  if (flags[b] == 0) return;   // uniform per block
  const int tid = threadIdx.x;
  const int wv = tid >> 6, lane = tid & 63;
  __shared__ unsigned long long spk[24];
  for (int w = tid; w < 24; w += 768) spk[w] = 0ULL;
  __syncthreads();
  float s0 = 0.f, s1 = 0.f, r0 = 0.f, r1 = 0.f;
  const int i0 = 2 * tid;
  const float* ub = U + (size_t)b * 512 * 1536 + i0;
  float2 u = *(const float2*)ub;
  for (int t = 0; t < 512; ++t) {
    float2 unext = u;
    if (t < 511) unext = *(const float2*)(ub + (size_t)(t + 1) * 1536);
    float a0 = fmaf(s0, KOEFF, u.x);
    float a1 = fmaf(s1, KOEFF, u.y);
    for (int wd = 0; wd < 24; ++wd) {
      unsigned long long m = spk[wd];
      while (m) {
        int bit = __ffsll(m) - 1;
        m &= m - 1;
        int jp = ((wd >> 1) << 7) + (bit << 1) + (wd & 1);
        float2 rv = *(const float2*)(WT2 + (size_t)jp * 1536 + i0);
        a0 += rv.x; a1 += rv.y;
      }
    }
    if (r0 > 0.f) a0 = 0.f;
    if (r1 > 0.f) a1 = 0.f;
    bool sp0 = a0 >= 1.0f, sp1 = a1 >= 1.0f;
    r0 -= 1.f; r1 -= 1.f;
    if (sp0) r0 = 2.f;
    if (sp1) r1 = 2.f;
    if (a0 < -1.f) a0 = -1.f;
    if (a1 < -1.f) a1 = -1.f;
    s0 = a0; s1 = a1;
    if (i0 >= 1280) {
      float* o = out + ((size_t)b * 256 + (i0 - 1280)) * 512 + t;
      o[0]   = sp0 ? 1.f : 0.f;
      o[512] = sp1 ? 1.f : 0.f;
    }
    __syncthreads();
    unsigned long long b0 = __ballot(sp0);
    unsigned long long b1 = __ballot(sp1);
    if (lane == 0) { spk[2 * wv] = b0; spk[2 * wv + 1] = b1; }
    __syncthreads();
    u = unext;
  }
}

// ---------------------------------------------------------------------------
// Fallback: WTF[j][i'] = W[512+i'][j] for all j in [0,2048)
// ---------------------------------------------------------------------------
__global__ __launch_bounds__(256) void k_wtf(const float* __restrict__ W, float* __restrict__ WTF) {
  __shared__ float tile[64][65];
  const int i0 = blockIdx.x * 64;
  const int j0 = blockIdx.y * 64;
  const float* src = W + (size_t)(512 + i0) * 2048 + j0;
  for (int e = threadIdx.x; e < 64 * 16; e += 256) {
    int r = e >> 4, c = e & 15;
    float4 v = *(const float4*)(src + (size_t)r * 2048 + c * 4);
    tile[r][c * 4 + 0] = v.x; tile[r][c * 4 + 1] = v.y;
    tile[r][c * 4 + 2] = v.z; tile[r][c * 4 + 3] = v.w;
  }
  __syncthreads();
  float* dst = WTF + (size_t)j0 * 1536 + i0;
  for (int e = threadIdx.x; e < 64 * 16; e += 256) {
    int jr = e >> 4, c = e & 15;
    float4 o;
    o.x = tile[c * 4 + 0][jr]; o.y = tile[c * 4 + 1][jr];
    o.z = tile[c * 4 + 2][jr]; o.w = tile[c * 4 + 3][jr];
    *(float4*)(dst + (size_t)jr * 1536 + c * 4) = o;
  }
}

// ---------------------------------------------------------------------------
// Fallback exact simulator (only when ws too small for fast path)
// ---------------------------------------------------------------------------
__global__ __launch_bounds__(256) void k_exact(const float* __restrict__ X, const float* __restrict__ W,
                                               const float* __restrict__ WTF, int use_wt,
                                               float* __restrict__ out) {
  const int b = blockIdx.x, tid = threadIdx.x;
  const int wv = tid >> 6, lane = tid & 63;
  float st[6], rf[6];
#pragma unroll
  for (int r = 0; r < 6; ++r) { st[r] = 0.f; rf[r] = 0.f; }
  __shared__ unsigned int mask[64];
  for (int w = tid; w < 64; w += 256) mask[w] = 0u;
  __syncthreads();
  for (int t = 0; t < 512; ++t) {
    {
      float x = X[((size_t)b * 512 + tid) * 512 + t];
      unsigned long long bl = __ballot(x > 0.5f);
      if (lane == 0) { mask[2 * wv] = (unsigned int)bl; mask[2 * wv + 1] = (unsigned int)(bl >> 32); }
      x = X[((size_t)b * 512 + 256 + tid) * 512 + t];
      bl = __ballot(x > 0.5f);
      if (lane == 0) { mask[8 + 2 * wv] = (unsigned int)bl; mask[9 + 2 * wv] = (unsigned int)(bl >> 32); }
    }
    __syncthreads();
    float add[6] = {0.f, 0.f, 0.f, 0.f, 0.f, 0.f};
    for (int wd = 0; wd < 64; ++wd) {
      unsigned int m = mask[wd];
      while (m) {
        int bitp = __ffs(m) - 1;
        m &= m - 1;
        int j = wd * 32 + bitp;
        if (use_wt) {
          const float* row = WTF + (size_t)j * 1536;
#pragma unroll
          for (int r = 0; r < 6; ++r) add[r] += row[tid + 256 * r];
        } else {
#pragma unroll
          for (int r = 0; r < 6; ++r) add[r] += W[(size_t)(512 + tid + 256 * r) * 2048 + j];
        }
      }
    }
    bool sp[6];
#pragma unroll
    for (int r = 0; r < 6; ++r) {
      float a = fmaf(st[r], KOEFF, add[r]);
      if (rf[r] > 0.f) a = 0.f;
      sp[r] = a >= 1.0f;
      rf[r] -= 1.f;
      if (sp[r]) rf[r] = 2.f;
      if (a < -1.f) a = -1.f;
      st[r] = a;
      int gi = 512 + tid + 256 * r;
      if (gi >= 1792) out[((size_t)b * 256 + (gi - 1792)) * 512 + t] = sp[r] ? 1.f : 0.f;
    }
    __syncthreads();
#pragma unroll
    for (int r = 0; r < 6; ++r) {
      unsigned long long bl = __ballot(sp[r]);
      if (lane == 0) {
        mask[16 + 8 * r + 2 * wv] = (unsigned int)bl;
        mask[17 + 8 * r + 2 * wv] = (unsigned int)(bl >> 32);
      }
    }
    __syncthreads();
  }
}

// ---------------------------------------------------------------------------
extern "C" void kernel_launch(void* const* d_in, const int* in_sizes, int n_in,
                              void* d_out, int out_size, void* d_ws, size_t ws_size,
                              hipStream_t stream) {
  const float* X = (const float*)d_in[0];   // [64][512][512]
  const float* W = (const float*)d_in[1];   // [2048][2048]
  float* out = (float*)d_out;               // [64][256][512]
  char* ws = (char*)d_ws;

  const size_t SZ_XT  = 64ull * 512 * 512 * 2;     // 33,554,432
  const size_t SZ_WH  = 1536ull * 512 * 2;         //  1,572,864
  const size_t SZ_WT2 = 1536ull * 1536 * 4;        //  9,437,184
  const size_t SZ_U   = 64ull * 512 * 1536 * 4;    // 201,326,592
  const size_t SZ_FL  = 256;                       // 64 int flags
  const size_t NEED_FULL = SZ_XT + 2 * SZ_WH + SZ_WT2 + SZ_U + SZ_FL;
  const size_t NEED_MID  = 2048ull * 1536 * 4;

  if (ws_size >= NEED_FULL) {
    u16*   XT  = (u16*)ws;
    u16*   Whi = (u16*)(ws + SZ_XT);
    u16*   Wlo = (u16*)(ws + SZ_XT + SZ_WH);
    float* WT2 = (float*)(ws + SZ_XT + 2 * SZ_WH);
    float* U   = (float*)(ws + SZ_XT + 2 * SZ_WH + SZ_WT2);
    int*   FL  = (int*)(ws + SZ_XT + 2 * SZ_WH + SZ_WT2 + SZ_U);
    k_xt<<<dim3(8, 8, 64), 256, 0, stream>>>(X, XT);
    k_wsplit<<<3072, 256, 0, stream>>>(W, Whi, Wlo, FL);
    k_wt2<<<dim3(24, 24), 256, 0, stream>>>(W, WT2);
    k_gemm<<<dim3(48, 64), 256, 0, stream>>>(Whi, Wlo, XT, U);
    k_lin<<<384, 256, 0, stream>>>(U, out, FL);
    k_fix<<<64, 768, 0, stream>>>(U, WT2, FL, out);
  } else if (ws_size >= NEED_MID) {
    float* WTF = (float*)ws;
    k_wtf<<<dim3(24, 32), 256, 0, stream>>>(W, WTF);
    k_exact<<<64, 256, 0, stream>>>(X, W, WTF, 1, out);
  } else {
    k_exact<<<64, 256, 0, stream>>>(X, W, nullptr, 0, out);
  }
}

// Round 3
// 344.672 us; speedup vs baseline: 2.9374x; 1.3459x over previous
//
#include <hip/hip_runtime.h>

// LIF constants (match reference)
#define KOEFF 0.951229424500714f
#define K64   0.040762204f        // KOEFF^64 = exp(-3.2)

typedef unsigned short u16;
typedef __attribute__((ext_vector_type(8))) short short8;   // 8 bf16 = 4 VGPRs (MFMA A/B frag)
typedef __attribute__((ext_vector_type(4))) float f32x4;    // MFMA C/D frag

__device__ __forceinline__ u16 f2bf(float f) {
  unsigned int v = __float_as_uint(f);
  unsigned int r = (v + 0x7FFFu + ((v >> 16) & 1u)) >> 16;
  return (u16)r;
}
__device__ __forceinline__ float bf2f(u16 u) {
  return __uint_as_float(((unsigned int)u) << 16);
}

// ---------------------------------------------------------------------------
// Kernel 1: X [64][512 j][512 t] fp32 -> XT16 [64][512 t][512 j] bf16
// ---------------------------------------------------------------------------
__global__ __launch_bounds__(256) void k_xt(const float* __restrict__ X, u16* __restrict__ XT) {
  __shared__ float tile[64][65];
  const int b  = blockIdx.z;
  const int j0 = blockIdx.x * 64;
  const int t0 = blockIdx.y * 64;
  const float* src = X + ((size_t)b * 512 + j0) * 512 + t0;
  for (int e = threadIdx.x; e < 64 * 16; e += 256) {
    int r = e >> 4, c = e & 15;
    float4 v = *(const float4*)(src + (size_t)r * 512 + c * 4);
    tile[r][c * 4 + 0] = v.x; tile[r][c * 4 + 1] = v.y;
    tile[r][c * 4 + 2] = v.z; tile[r][c * 4 + 3] = v.w;
  }
  __syncthreads();
  u16* dst = XT + ((size_t)b * 512 + t0) * 512 + j0;
  for (int e = threadIdx.x; e < 64 * 16; e += 256) {
    int tr = e >> 4, c = e & 15;
    ushort4 o;
    o.x = f2bf(tile[c * 4 + 0][tr]); o.y = f2bf(tile[c * 4 + 1][tr]);
    o.z = f2bf(tile[c * 4 + 2][tr]); o.w = f2bf(tile[c * 4 + 3][tr]);
    *(ushort4*)(dst + (size_t)tr * 512 + c * 4) = o;
  }
}

// ---------------------------------------------------------------------------
// Kernel 2: W rows 512..2047, cols 0..511 -> bf16 hi/lo split [1536][512]
// Also zeroes the 64 per-batch spike flags (block 0).
// ---------------------------------------------------------------------------
__global__ __launch_bounds__(256) void k_wsplit(const float* __restrict__ W,
                                                u16* __restrict__ Whi, u16* __restrict__ Wlo,
                                                int* __restrict__ flags) {
  if (blockIdx.x == 0 && threadIdx.x < 64) flags[threadIdx.x] = 0;
  int p = blockIdx.x * 256 + threadIdx.x;
  if (p >= 1536 * 512) return;
  int i = p >> 9, j = p & 511;
  float w = W[(size_t)(512 + i) * 2048 + j];
  u16 hi = f2bf(w);
  Whi[p] = hi;
  Wlo[p] = f2bf(w - bf2f(hi));
}

// ---------------------------------------------------------------------------
// Kernel 3: WT2[j'][i'] = W[512+i'][512+j']  (recurrent block, transposed)
// ---------------------------------------------------------------------------
__global__ __launch_bounds__(256) void k_wt2(const float* __restrict__ W, float* __restrict__ WT2) {
  __shared__ float tile[64][65];
  const int i0 = blockIdx.x * 64;
  const int j0 = blockIdx.y * 64;
  const float* src = W + (size_t)(512 + i0) * 2048 + 512 + j0;
  for (int e = threadIdx.x; e < 64 * 16; e += 256) {
    int r = e >> 4, c = e & 15;
    float4 v = *(const float4*)(src + (size_t)r * 2048 + c * 4);
    tile[r][c * 4 + 0] = v.x; tile[r][c * 4 + 1] = v.y;
    tile[r][c * 4 + 2] = v.z; tile[r][c * 4 + 3] = v.w;
  }
  __syncthreads();
  float* dst = WT2 + (size_t)j0 * 1536 + i0;
  for (int e = threadIdx.x; e < 64 * 16; e += 256) {
    int jr = e >> 4, c = e & 15;
    float4 o;
    o.x = tile[c * 4 + 0][jr]; o.y = tile[c * 4 + 1][jr];
    o.z = tile[c * 4 + 2][jr]; o.w = tile[c * 4 + 3][jr];
    *(float4*)(dst + (size_t)jr * 1536 + c * 4) = o;
  }
}

// ---------------------------------------------------------------------------
// Kernel 4: U[b][t][i'] = sum_j (Whi+Wlo)[i'][j] * XT16[b][t][j]  (fp32 MFMA)
// ---------------------------------------------------------------------------
__global__ __launch_bounds__(256) void k_gemm(const u16* __restrict__ Ahi, const u16* __restrict__ Alo,
                                              const u16* __restrict__ Bx, float* __restrict__ U) {
  __shared__ u16 lAhi[128 * 64];
  __shared__ u16 lAlo[128 * 64];
  __shared__ u16 lB[128 * 64];
  const int b    = blockIdx.y;
  const int mt   = blockIdx.x >> 2;
  const int nt   = blockIdx.x & 3;
  const int tid  = threadIdx.x;
  const int wv   = tid >> 6;
  const int lane = tid & 63;
  const int wr   = wv >> 1, wc = wv & 1;

  f32x4 acc[4][4];
#pragma unroll
  for (int mi = 0; mi < 4; ++mi)
#pragma unroll
    for (int ni = 0; ni < 4; ++ni) acc[mi][ni] = (f32x4)0.0f;

  const u16* gAh = Ahi + (size_t)mt * 128 * 512;
  const u16* gAl = Alo + (size_t)mt * 128 * 512;
  const u16* gB  = Bx + ((size_t)b * 512 + nt * 128) * 512;

  for (int k0 = 0; k0 < 512; k0 += 64) {
#pragma unroll
    for (int it = 0; it < 4; ++it) {
      int byteoff = wv * 4096 + it * 1024 + lane * 16;
      int row  = byteoff >> 7;
      int ksub = ((byteoff >> 4) & 7) * 8;
      int ldsoff = wv * 2048 + it * 512;
      __builtin_amdgcn_global_load_lds(
          (const __attribute__((address_space(1))) void*)(gAh + (size_t)row * 512 + k0 + ksub),
          (__attribute__((address_space(3))) void*)(lAhi + ldsoff), 16, 0, 0);
      __builtin_amdgcn_global_load_lds(
          (const __attribute__((address_space(1))) void*)(gAl + (size_t)row * 512 + k0 + ksub),
          (__attribute__((address_space(3))) void*)(lAlo + ldsoff), 16, 0, 0);
      __builtin_amdgcn_global_load_lds(
          (const __attribute__((address_space(1))) void*)(gB + (size_t)row * 512 + k0 + ksub),
          (__attribute__((address_space(3))) void*)(lB + ldsoff), 16, 0, 0);
    }
    __syncthreads();
#pragma unroll
    for (int kk = 0; kk < 2; ++kk) {
      short8 ah[4], al[4], bb[4];
      const int krow = kk * 32 + (lane >> 4) * 8;
#pragma unroll
      for (int mi = 0; mi < 4; ++mi) {
        int m = wr * 64 + mi * 16 + (lane & 15);
        ah[mi] = *(const short8*)&lAhi[m * 64 + krow];
        al[mi] = *(const short8*)&lAlo[m * 64 + krow];
      }
#pragma unroll
      for (int ni = 0; ni < 4; ++ni) {
        int n = wc * 64 + ni * 16 + (lane & 15);
        bb[ni] = *(const short8*)&lB[n * 64 + krow];
      }
#pragma unroll
      for (int mi = 0; mi < 4; ++mi)
#pragma unroll
        for (int ni = 0; ni < 4; ++ni) {
          acc[mi][ni] = __builtin_amdgcn_mfma_f32_16x16x32_bf16(ah[mi], bb[ni], acc[mi][ni], 0, 0, 0);
          acc[mi][ni] = __builtin_amdgcn_mfma_f32_16x16x32_bf16(al[mi], bb[ni], acc[mi][ni], 0, 0, 0);
        }
    }
    __syncthreads();
  }
#pragma unroll
  for (int mi = 0; mi < 4; ++mi) {
    int ib = mt * 128 + wr * 64 + mi * 16 + ((lane >> 4) << 2);
#pragma unroll
    for (int ni = 0; ni < 4; ++ni) {
      int t = nt * 128 + wc * 64 + ni * 16 + (lane & 15);
      *(f32x4*)(U + ((size_t)b * 512 + t) * 1536 + ib) = acc[mi][ni];
    }
  }
}

// ---------------------------------------------------------------------------
// Kernel 5a: per-chunk partial linear scan (speculative, no nonlinearity).
// Thread (b, c, i): p_c = sum_{j=0..63} K^{63-j} * U[b][c*64+j][i] -> P[b][c][i]
// Grid dim3(6, 8, 64): full-occupancy streaming of U.
// ---------------------------------------------------------------------------
__global__ __launch_bounds__(256) void k_part(const float* __restrict__ U, float* __restrict__ P) {
  const int i = blockIdx.x * 256 + threadIdx.x;   // 0..1535
  const int c = blockIdx.y, b = blockIdx.z;
  const float* up = U + ((size_t)b * 512 + c * 64) * 1536 + i;
  float s = 0.f;
  float buf[8];
#pragma unroll
  for (int j = 0; j < 8; ++j) buf[j] = up[(size_t)j * 1536];
  for (int t0 = 0; t0 < 64; t0 += 8) {
#pragma unroll
    for (int j = 0; j < 8; ++j) {
      float u = buf[j];
      if (t0 + 8 < 64) buf[j] = up[(size_t)(t0 + 8 + j) * 1536];
      s = fmaf(s, KOEFF, u);
    }
  }
  P[((size_t)b * 8 + c) * 1536 + i] = s;
}

// ---------------------------------------------------------------------------
// Kernel 5b: chunk walk. Reconstruct chunk-start state from P (affine chain),
// walk 64 steps linearly, emit spike outputs for i>=1280, flag any violation
// (s >= 1 spike, or s < -1 clamp) -> batch recomputed exactly by k_fix.
// Before the first violation, linear dynamics == exact dynamics.
// ---------------------------------------------------------------------------
__global__ __launch_bounds__(256) void k_chunk(const float* __restrict__ U, const float* __restrict__ P,
                                               float* __restrict__ out, int* __restrict__ flags) {
  const int i = blockIdx.x * 256 + threadIdx.x;   // 0..1535
  const int c = blockIdx.y, b = blockIdx.z;
  // chunk-start state: s_{cL} = sum_{d<c} (K^64)^{c-1-d} * p_d
  float s = 0.f;
  const float* pp = P + (size_t)b * 8 * 1536 + i;
  for (int d = 0; d < c; ++d) s = fmaf(s, K64, pp[(size_t)d * 1536]);

  const float* up = U + ((size_t)b * 512 + c * 64) * 1536 + i;
  const bool wr = (i >= 1280);
  float* op = out + ((size_t)b * 256 + (i - 1280)) * 512 + c * 64;  // valid only if wr
  bool viol = false;
  float buf[8];
#pragma unroll
  for (int j = 0; j < 8; ++j) buf[j] = up[(size_t)j * 1536];
  for (int t0 = 0; t0 < 64; t0 += 8) {
    float spv[8];
#pragma unroll
    for (int j = 0; j < 8; ++j) {
      float u = buf[j];
      if (t0 + 8 < 64) buf[j] = up[(size_t)(t0 + 8 + j) * 1536];
      s = fmaf(s, KOEFF, u);
      bool sp = (s >= 1.0f);
      viol = viol || sp || (s < -1.0f);
      spv[j] = sp ? 1.f : 0.f;
    }
    if (wr) {
      *(float4*)(op + t0)     = make_float4(spv[0], spv[1], spv[2], spv[3]);
      *(float4*)(op + t0 + 4) = make_float4(spv[4], spv[5], spv[6], spv[7]);
    }
  }
  if (viol) atomicOr(&flags[b], 1);
}

// ---------------------------------------------------------------------------
// Kernel 6: exact sequential scan, gated per batch on spike flag.
// Expected: immediate exit for all batches. Correctness backstop.
// ---------------------------------------------------------------------------
__global__ __launch_bounds__(768) void k_fix(const float* __restrict__ U, const float* __restrict__ WT2,
                                             const int* __restrict__ flags, float* __restrict__ out) {
  const int b = blockIdx.x;
  if (flags[b] == 0) return;   // uniform per block
  const int tid = threadIdx.x;
  const int wv = tid >> 6, lane = tid & 63;
  __shared__ unsigned long long spk[24];
  for (int w = tid; w < 24; w += 768) spk[w] = 0ULL;
  __syncthreads();
  float s0 = 0.f, s1 = 0.f, r0 = 0.f, r1 = 0.f;
  const int i0 = 2 * tid;
  const float* ub = U + (size_t)b * 512 * 1536 + i0;
  float2 u = *(const float2*)ub;
  for (int t = 0; t < 512; ++t) {
    float2 unext = u;
    if (t < 511) unext = *(const float2*)(ub + (size_t)(t + 1) * 1536);
    float a0 = fmaf(s0, KOEFF, u.x);
    float a1 = fmaf(s1, KOEFF, u.y);
    for (int wd = 0; wd < 24; ++wd) {
      unsigned long long m = spk[wd];
      while (m) {
        int bit = __ffsll(m) - 1;
        m &= m - 1;
        int jp = ((wd >> 1) << 7) + (bit << 1) + (wd & 1);
        float2 rv = *(const float2*)(WT2 + (size_t)jp * 1536 + i0);
        a0 += rv.x; a1 += rv.y;
      }
    }
    if (r0 > 0.f) a0 = 0.f;
    if (r1 > 0.f) a1 = 0.f;
    bool sp0 = a0 >= 1.0f, sp1 = a1 >= 1.0f;
    r0 -= 1.f; r1 -= 1.f;
    if (sp0) r0 = 2.f;
    if (sp1) r1 = 2.f;
    if (a0 < -1.f) a0 = -1.f;
    if (a1 < -1.f) a1 = -1.f;
    s0 = a0; s1 = a1;
    if (i0 >= 1280) {
      float* o = out + ((size_t)b * 256 + (i0 - 1280)) * 512 + t;
      o[0]   = sp0 ? 1.f : 0.f;
      o[512] = sp1 ? 1.f : 0.f;
    }
    __syncthreads();
    unsigned long long b0 = __ballot(sp0);
    unsigned long long b1 = __ballot(sp1);
    if (lane == 0) { spk[2 * wv] = b0; spk[2 * wv + 1] = b1; }
    __syncthreads();
    u = unext;
  }
}

// ---------------------------------------------------------------------------
// Fallback: WTF[j][i'] = W[512+i'][j] for all j in [0,2048)
// ---------------------------------------------------------------------------
__global__ __launch_bounds__(256) void k_wtf(const float* __restrict__ W, float* __restrict__ WTF) {
  __shared__ float tile[64][65];
  const int i0 = blockIdx.x * 64;
  const int j0 = blockIdx.y * 64;
  const float* src = W + (size_t)(512 + i0) * 2048 + j0;
  for (int e = threadIdx.x; e < 64 * 16; e += 256) {
    int r = e >> 4, c = e & 15;
    float4 v = *(const float4*)(src + (size_t)r * 2048 + c * 4);
    tile[r][c * 4 + 0] = v.x; tile[r][c * 4 + 1] = v.y;
    tile[r][c * 4 + 2] = v.z; tile[r][c * 4 + 3] = v.w;
  }
  __syncthreads();
  float* dst = WTF + (size_t)j0 * 1536 + i0;
  for (int e = threadIdx.x; e < 64 * 16; e += 256) {
    int jr = e >> 4, c = e & 15;
    float4 o;
    o.x = tile[c * 4 + 0][jr]; o.y = tile[c * 4 + 1][jr];
    o.z = tile[c * 4 + 2][jr]; o.w = tile[c * 4 + 3][jr];
    *(float4*)(dst + (size_t)jr * 1536 + c * 4) = o;
  }
}

// ---------------------------------------------------------------------------
// Fallback exact simulator (only when ws too small for fast path)
// ---------------------------------------------------------------------------
__global__ __launch_bounds__(256) void k_exact(const float* __restrict__ X, const float* __restrict__ W,
                                               const float* __restrict__ WTF, int use_wt,
                                               float* __restrict__ out) {
  const int b = blockIdx.x, tid = threadIdx.x;
  const int wv = tid >> 6, lane = tid & 63;
  float st[6], rf[6];
#pragma unroll
  for (int r = 0; r < 6; ++r) { st[r] = 0.f; rf[r] = 0.f; }
  __shared__ unsigned int mask[64];
  for (int w = tid; w < 64; w += 256) mask[w] = 0u;
  __syncthreads();
  for (int t = 0; t < 512; ++t) {
    {
      float x = X[((size_t)b * 512 + tid) * 512 + t];
      unsigned long long bl = __ballot(x > 0.5f);
      if (lane == 0) { mask[2 * wv] = (unsigned int)bl; mask[2 * wv + 1] = (unsigned int)(bl >> 32); }
      x = X[((size_t)b * 512 + 256 + tid) * 512 + t];
      bl = __ballot(x > 0.5f);
      if (lane == 0) { mask[8 + 2 * wv] = (unsigned int)bl; mask[9 + 2 * wv] = (unsigned int)(bl >> 32); }
    }
    __syncthreads();
    float add[6] = {0.f, 0.f, 0.f, 0.f, 0.f, 0.f};
    for (int wd = 0; wd < 64; ++wd) {
      unsigned int m = mask[wd];
      while (m) {
        int bitp = __ffs(m) - 1;
        m &= m - 1;
        int j = wd * 32 + bitp;
        if (use_wt) {
          const float* row = WTF + (size_t)j * 1536;
#pragma unroll
          for (int r = 0; r < 6; ++r) add[r] += row[tid + 256 * r];
        } else {
#pragma unroll
          for (int r = 0; r < 6; ++r) add[r] += W[(size_t)(512 + tid + 256 * r) * 2048 + j];
        }
      }
    }
    bool sp[6];
#pragma unroll
    for (int r = 0; r < 6; ++r) {
      float a = fmaf(st[r], KOEFF, add[r]);
      if (rf[r] > 0.f) a = 0.f;
      sp[r] = a >= 1.0f;
      rf[r] -= 1.f;
      if (sp[r]) rf[r] = 2.f;
      if (a < -1.f) a = -1.f;
      st[r] = a;
      int gi = 512 + tid + 256 * r;
      if (gi >= 1792) out[((size_t)b * 256 + (gi - 1792)) * 512 + t] = sp[r] ? 1.f : 0.f;
    }
    __syncthreads();
#pragma unroll
    for (int r = 0; r < 6; ++r) {
      unsigned long long bl = __ballot(sp[r]);
      if (lane == 0) {
        mask[16 + 8 * r + 2 * wv] = (unsigned int)bl;
        mask[17 + 8 * r + 2 * wv] = (unsigned int)(bl >> 32);
      }
    }
    __syncthreads();
  }
}

// ---------------------------------------------------------------------------
extern "C" void kernel_launch(void* const* d_in, const int* in_sizes, int n_in,
                              void* d_out, int out_size, void* d_ws, size_t ws_size,
                              hipStream_t stream) {
  const float* X = (const float*)d_in[0];   // [64][512][512]
  const float* W = (const float*)d_in[1];   // [2048][2048]
  float* out = (float*)d_out;               // [64][256][512]
  char* ws = (char*)d_ws;

  const size_t SZ_XT  = 64ull * 512 * 512 * 2;     // 33,554,432
  const size_t SZ_WH  = 1536ull * 512 * 2;         //  1,572,864
  const size_t SZ_WT2 = 1536ull * 1536 * 4;        //  9,437,184
  const size_t SZ_U   = 64ull * 512 * 1536 * 4;    // 201,326,592
  const size_t SZ_P   = 64ull * 8 * 1536 * 4;      //  3,145,728
  const size_t SZ_FL  = 256;                       // 64 int flags
  const size_t NEED_FULL = SZ_XT + 2 * SZ_WH + SZ_WT2 + SZ_U + SZ_P + SZ_FL;
  const size_t NEED_MID  = 2048ull * 1536 * 4;

  if (ws_size >= NEED_FULL) {
    u16*   XT  = (u16*)ws;
    u16*   Whi = (u16*)(ws + SZ_XT);
    u16*   Wlo = (u16*)(ws + SZ_XT + SZ_WH);
    float* WT2 = (float*)(ws + SZ_XT + 2 * SZ_WH);
    float* U   = (float*)(ws + SZ_XT + 2 * SZ_WH + SZ_WT2);
    float* P   = (float*)(ws + SZ_XT + 2 * SZ_WH + SZ_WT2 + SZ_U);
    int*   FL  = (int*)(ws + SZ_XT + 2 * SZ_WH + SZ_WT2 + SZ_U + SZ_P);
    k_xt<<<dim3(8, 8, 64), 256, 0, stream>>>(X, XT);
    k_wsplit<<<3072, 256, 0, stream>>>(W, Whi, Wlo, FL);
    k_wt2<<<dim3(24, 24), 256, 0, stream>>>(W, WT2);
    k_gemm<<<dim3(48, 64), 256, 0, stream>>>(Whi, Wlo, XT, U);
    k_part<<<dim3(6, 8, 64), 256, 0, stream>>>(U, P);
    k_chunk<<<dim3(6, 8, 64), 256, 0, stream>>>(U, P, out, FL);
    k_fix<<<64, 768, 0, stream>>>(U, WT2, FL, out);
  } else if (ws_size >= NEED_MID) {
    float* WTF = (float*)ws;
    k_wtf<<<dim3(24, 32), 256, 0, stream>>>(W, WTF);
    k_exact<<<64, 256, 0, stream>>>(X, W, WTF, 1, out);
  } else {
    k_exact<<<64, 256, 0, stream>>>(X, W, nullptr, 0, out);
  }
}

// Round 4
// 252.001 us; speedup vs baseline: 4.0177x; 1.3677x over previous
//
#include <hip/hip_runtime.h>

// LIF constants (match reference)
#define KOEFF 0.951229424500714f
#define K64   0.040762204f        // KOEFF^64 = exp(-3.2)

typedef unsigned short u16;
typedef __attribute__((ext_vector_type(8))) short short8;   // 8 bf16 = 4 VGPRs (MFMA A/B frag)
typedef __attribute__((ext_vector_type(4))) float f32x4;    // MFMA C/D frag

__device__ __forceinline__ u16 f2bf(float f) {
  unsigned int v = __float_as_uint(f);
  unsigned int r = (v + 0x7FFFu + ((v >> 16) & 1u)) >> 16;
  return (u16)r;
}
__device__ __forceinline__ float bf2f(u16 u) {
  return __uint_as_float(((unsigned int)u) << 16);
}

// ---------------------------------------------------------------------------
// Kernel 1: X [64][512 j][512 t] fp32 -> XT16 [64][512 t][512 j] bf16
// ---------------------------------------------------------------------------
__global__ __launch_bounds__(256) void k_xt(const float* __restrict__ X, u16* __restrict__ XT) {
  __shared__ float tile[64][65];
  const int b  = blockIdx.z;
  const int j0 = blockIdx.x * 64;
  const int t0 = blockIdx.y * 64;
  const float* src = X + ((size_t)b * 512 + j0) * 512 + t0;
  for (int e = threadIdx.x; e < 64 * 16; e += 256) {
    int r = e >> 4, c = e & 15;
    float4 v = *(const float4*)(src + (size_t)r * 512 + c * 4);
    tile[r][c * 4 + 0] = v.x; tile[r][c * 4 + 1] = v.y;
    tile[r][c * 4 + 2] = v.z; tile[r][c * 4 + 3] = v.w;
  }
  __syncthreads();
  u16* dst = XT + ((size_t)b * 512 + t0) * 512 + j0;
  for (int e = threadIdx.x; e < 64 * 16; e += 256) {
    int tr = e >> 4, c = e & 15;
    ushort4 o;
    o.x = f2bf(tile[c * 4 + 0][tr]); o.y = f2bf(tile[c * 4 + 1][tr]);
    o.z = f2bf(tile[c * 4 + 2][tr]); o.w = f2bf(tile[c * 4 + 3][tr]);
    *(ushort4*)(dst + (size_t)tr * 512 + c * 4) = o;
  }
}

// ---------------------------------------------------------------------------
// Kernel 2: W rows 512..2047, cols 0..511 -> bf16 [1536][512]; zero flags.
// ---------------------------------------------------------------------------
__global__ __launch_bounds__(256) void k_wcvt(const float* __restrict__ W,
                                              u16* __restrict__ Whi, int* __restrict__ flags) {
  if (blockIdx.x == 0 && threadIdx.x < 64) flags[threadIdx.x] = 0;
  int p = blockIdx.x * 256 + threadIdx.x;
  if (p >= 1536 * 512) return;
  int i = p >> 9, j = p & 511;
  Whi[p] = f2bf(W[(size_t)(512 + i) * 2048 + j]);
}

// ---------------------------------------------------------------------------
// Kernel 3: WT2[j'][i'] = W[512+i'][512+j']  (recurrent block, transposed)
// ---------------------------------------------------------------------------
__global__ __launch_bounds__(256) void k_wt2(const float* __restrict__ W, float* __restrict__ WT2) {
  __shared__ float tile[64][65];
  const int i0 = blockIdx.x * 64;
  const int j0 = blockIdx.y * 64;
  const float* src = W + (size_t)(512 + i0) * 2048 + 512 + j0;
  for (int e = threadIdx.x; e < 64 * 16; e += 256) {
    int r = e >> 4, c = e & 15;
    float4 v = *(const float4*)(src + (size_t)r * 2048 + c * 4);
    tile[r][c * 4 + 0] = v.x; tile[r][c * 4 + 1] = v.y;
    tile[r][c * 4 + 2] = v.z; tile[r][c * 4 + 3] = v.w;
  }
  __syncthreads();
  float* dst = WT2 + (size_t)j0 * 1536 + i0;
  for (int e = threadIdx.x; e < 64 * 16; e += 256) {
    int jr = e >> 4, c = e & 15;
    float4 o;
    o.x = tile[c * 4 + 0][jr]; o.y = tile[c * 4 + 1][jr];
    o.z = tile[c * 4 + 2][jr]; o.w = tile[c * 4 + 3][jr];
    *(float4*)(dst + (size_t)jr * 1536 + c * 4) = o;
  }
}

// ---------------------------------------------------------------------------
// Kernel 4: U16[b][t][i'] = bf16( sum_j Whi[i'][j] * XT16[b][t][j] )
// 128x128 tile, BK=64, 4 waves each 64x64. T2 XOR-swizzle via pre-swizzled
// global source (rule #21: linear LDS dest for global_load_lds + same XOR
// on the ds_read address).
// ---------------------------------------------------------------------------
__global__ __launch_bounds__(256) void k_gemm(const u16* __restrict__ A,
                                              const u16* __restrict__ Bx, u16* __restrict__ U) {
  __shared__ u16 lA[128 * 64];
  __shared__ u16 lB[128 * 64];
  const int b    = blockIdx.y;
  const int mt   = blockIdx.x >> 2;
  const int nt   = blockIdx.x & 3;
  const int tid  = threadIdx.x;
  const int wv   = tid >> 6;
  const int lane = tid & 63;
  const int wr   = wv >> 1, wc = wv & 1;

  f32x4 acc[4][4];
#pragma unroll
  for (int mi = 0; mi < 4; ++mi)
#pragma unroll
    for (int ni = 0; ni < 4; ++ni) acc[mi][ni] = (f32x4)0.0f;

  const u16* gA = A + (size_t)mt * 128 * 512;
  const u16* gB = Bx + ((size_t)b * 512 + nt * 128) * 512;

  for (int k0 = 0; k0 < 512; k0 += 64) {
#pragma unroll
    for (int it = 0; it < 4; ++it) {
      int byteoff = wv * 4096 + it * 1024 + lane * 16;
      int row   = byteoff >> 7;          // 128B per LDS row (64 bf16 of k)
      int chunk = (byteoff >> 4) & 7;    // 16B chunk within row
      int ksub  = (chunk ^ (row & 7)) * 8;   // pre-swizzled global source
      int ldsoff = wv * 2048 + it * 512;     // u16 elems, wave-uniform (linear dest)
      __builtin_amdgcn_global_load_lds(
          (const __attribute__((address_space(1))) void*)(gA + (size_t)row * 512 + k0 + ksub),
          (__attribute__((address_space(3))) void*)(lA + ldsoff), 16, 0, 0);
      __builtin_amdgcn_global_load_lds(
          (const __attribute__((address_space(1))) void*)(gB + (size_t)row * 512 + k0 + ksub),
          (__attribute__((address_space(3))) void*)(lB + ldsoff), 16, 0, 0);
    }
    __syncthreads();
#pragma unroll
    for (int kk = 0; kk < 2; ++kk) {
      short8 ah[4], bb[4];
      const int kc = kk * 4 + (lane >> 4);   // chunk index 0..7
      const int sw = lane & 7;               // == (row&7) for our rows
#pragma unroll
      for (int mi = 0; mi < 4; ++mi) {
        int m = wr * 64 + mi * 16 + (lane & 15);
        ah[mi] = *(const short8*)&lA[m * 64 + ((kc ^ sw) << 3)];
      }
#pragma unroll
      for (int ni = 0; ni < 4; ++ni) {
        int n = wc * 64 + ni * 16 + (lane & 15);
        bb[ni] = *(const short8*)&lB[n * 64 + ((kc ^ sw) << 3)];
      }
#pragma unroll
      for (int mi = 0; mi < 4; ++mi)
#pragma unroll
        for (int ni = 0; ni < 4; ++ni)
          acc[mi][ni] = __builtin_amdgcn_mfma_f32_16x16x32_bf16(ah[mi], bb[ni], acc[mi][ni], 0, 0, 0);
    }
    __syncthreads();
  }
  // epilogue: D layout col=lane&15 (n=t), row=(lane>>4)*4+q (m=i); bf16 store
#pragma unroll
  for (int mi = 0; mi < 4; ++mi) {
    int ib = mt * 128 + wr * 64 + mi * 16 + ((lane >> 4) << 2);
#pragma unroll
    for (int ni = 0; ni < 4; ++ni) {
      int t = nt * 128 + wc * 64 + ni * 16 + (lane & 15);
      f32x4 v = acc[mi][ni];
      ushort4 o;
      o.x = f2bf(v.x); o.y = f2bf(v.y); o.z = f2bf(v.z); o.w = f2bf(v.w);
      *(ushort4*)(U + ((size_t)b * 512 + t) * 1536 + ib) = o;
    }
  }
}

// ---------------------------------------------------------------------------
// Kernel 5a: per-chunk partial linear scan over bf16 U. Thread handles 2
// adjacent neurons (uint = 2x bf16 per step -> 256B/wave coalescing).
// p_c = sum_{j=0..63} K^{63-j} * U[b][c*64+j][i] -> P[b][c][i]
// ---------------------------------------------------------------------------
__global__ __launch_bounds__(256) void k_part(const u16* __restrict__ U, float* __restrict__ P) {
  const int g = blockIdx.x * 256 + threadIdx.x;   // 0..767
  const int i = g * 2;
  const int c = blockIdx.y, b = blockIdx.z;
  const u16* up = U + ((size_t)b * 512 + c * 64) * 1536 + i;
  float s0 = 0.f, s1 = 0.f;
  unsigned int buf[8];
#pragma unroll
  for (int j = 0; j < 8; ++j) buf[j] = *(const unsigned int*)(up + (size_t)j * 1536);
  for (int t0 = 0; t0 < 64; t0 += 8) {
#pragma unroll
    for (int j = 0; j < 8; ++j) {
      unsigned int u = buf[j];
      if (t0 + 8 < 64) buf[j] = *(const unsigned int*)(up + (size_t)(t0 + 8 + j) * 1536);
      s0 = fmaf(s0, KOEFF, bf2f((u16)(u & 0xffffu)));
      s1 = fmaf(s1, KOEFF, bf2f((u16)(u >> 16)));
    }
  }
  *(float2*)(P + ((size_t)b * 8 + c) * 1536 + i) = make_float2(s0, s1);
}

// ---------------------------------------------------------------------------
// Kernel 5b: chunk walk over bf16 U, 2 neurons/thread. Reconstruct
// chunk-start state from P, walk 64 steps linearly, emit spikes for
// i>=1280, flag any violation (spike or clamp) -> batch redone by k_fix.
// ---------------------------------------------------------------------------
__global__ __launch_bounds__(256) void k_chunk(const u16* __restrict__ U, const float* __restrict__ P,
                                               float* __restrict__ out, int* __restrict__ flags) {
  const int g = blockIdx.x * 256 + threadIdx.x;   // 0..767
  const int i = g * 2;
  const int c = blockIdx.y, b = blockIdx.z;
  float s0 = 0.f, s1 = 0.f;
  const float* pp = P + (size_t)b * 8 * 1536 + i;
  for (int d = 0; d < c; ++d) {
    float2 pv = *(const float2*)(pp + (size_t)d * 1536);
    s0 = fmaf(s0, K64, pv.x);
    s1 = fmaf(s1, K64, pv.y);
  }
  const u16* up = U + ((size_t)b * 512 + c * 64) * 1536 + i;
  const bool wr = (i >= 1280);
  float* op = out + ((size_t)b * 256 + (i - 1280)) * 512 + c * 64;  // valid only if wr
  bool viol = false;
  unsigned int buf[8];
#pragma unroll
  for (int j = 0; j < 8; ++j) buf[j] = *(const unsigned int*)(up + (size_t)j * 1536);
  for (int t0 = 0; t0 < 64; t0 += 8) {
    float sp0[8], sp1[8];
#pragma unroll
    for (int j = 0; j < 8; ++j) {
      unsigned int u = buf[j];
      if (t0 + 8 < 64) buf[j] = *(const unsigned int*)(up + (size_t)(t0 + 8 + j) * 1536);
      s0 = fmaf(s0, KOEFF, bf2f((u16)(u & 0xffffu)));
      s1 = fmaf(s1, KOEFF, bf2f((u16)(u >> 16)));
      bool a = (s0 >= 1.0f), bsp = (s1 >= 1.0f);
      viol = viol || a || bsp || (s0 < -1.0f) || (s1 < -1.0f);
      sp0[j] = a ? 1.f : 0.f;
      sp1[j] = bsp ? 1.f : 0.f;
    }
    if (wr) {
      *(float4*)(op + t0)           = make_float4(sp0[0], sp0[1], sp0[2], sp0[3]);
      *(float4*)(op + t0 + 4)       = make_float4(sp0[4], sp0[5], sp0[6], sp0[7]);
      *(float4*)(op + 512 + t0)     = make_float4(sp1[0], sp1[1], sp1[2], sp1[3]);
      *(float4*)(op + 512 + t0 + 4) = make_float4(sp1[4], sp1[5], sp1[6], sp1[7]);
    }
  }
  if (viol) atomicOr(&flags[b], 1);
}

// ---------------------------------------------------------------------------
// Kernel 6: exact sequential scan (bf16 U), gated per batch on spike flag.
// Expected: immediate exit for all batches. Correctness backstop.
// ---------------------------------------------------------------------------
__global__ __launch_bounds__(768) void k_fix(const u16* __restrict__ U, const float* __restrict__ WT2,
                                             const int* __restrict__ flags, float* __restrict__ out) {
  const int b = blockIdx.x;
  if (flags[b] == 0) return;   // uniform per block
  const int tid = threadIdx.x;
  const int wv = tid >> 6, lane = tid & 63;
  __shared__ unsigned long long spk[24];
  for (int w = tid; w < 24; w += 768) spk[w] = 0ULL;
  __syncthreads();
  float s0 = 0.f, s1 = 0.f, r0 = 0.f, r1 = 0.f;
  const int i0 = 2 * tid;
  const u16* ub = U + (size_t)b * 512 * 1536 + i0;
  unsigned int u = *(const unsigned int*)ub;
  for (int t = 0; t < 512; ++t) {
    unsigned int unext = u;
    if (t < 511) unext = *(const unsigned int*)(ub + (size_t)(t + 1) * 1536);
    float a0 = fmaf(s0, KOEFF, bf2f((u16)(u & 0xffffu)));
    float a1 = fmaf(s1, KOEFF, bf2f((u16)(u >> 16)));
    for (int wd = 0; wd < 24; ++wd) {
      unsigned long long m = spk[wd];
      while (m) {
        int bit = __ffsll(m) - 1;
        m &= m - 1;
        int jp = ((wd >> 1) << 7) + (bit << 1) + (wd & 1);
        float2 rv = *(const float2*)(WT2 + (size_t)jp * 1536 + i0);
        a0 += rv.x; a1 += rv.y;
      }
    }
    if (r0 > 0.f) a0 = 0.f;
    if (r1 > 0.f) a1 = 0.f;
    bool sp0 = a0 >= 1.0f, sp1 = a1 >= 1.0f;
    r0 -= 1.f; r1 -= 1.f;
    if (sp0) r0 = 2.f;
    if (sp1) r1 = 2.f;
    if (a0 < -1.f) a0 = -1.f;
    if (a1 < -1.f) a1 = -1.f;
    s0 = a0; s1 = a1;
    if (i0 >= 1280) {
      float* o = out + ((size_t)b * 256 + (i0 - 1280)) * 512 + t;
      o[0]   = sp0 ? 1.f : 0.f;
      o[512] = sp1 ? 1.f : 0.f;
    }
    __syncthreads();
    unsigned long long b0 = __ballot(sp0);
    unsigned long long b1 = __ballot(sp1);
    if (lane == 0) { spk[2 * wv] = b0; spk[2 * wv + 1] = b1; }
    __syncthreads();
    u = unext;
  }
}

// ---------------------------------------------------------------------------
// Fallback: WTF[j][i'] = W[512+i'][j] for all j in [0,2048)
// ---------------------------------------------------------------------------
__global__ __launch_bounds__(256) void k_wtf(const float* __restrict__ W, float* __restrict__ WTF) {
  __shared__ float tile[64][65];
  const int i0 = blockIdx.x * 64;
  const int j0 = blockIdx.y * 64;
  const float* src = W + (size_t)(512 + i0) * 2048 + j0;
  for (int e = threadIdx.x; e < 64 * 16; e += 256) {
    int r = e >> 4, c = e & 15;
    float4 v = *(const float4*)(src + (size_t)r * 2048 + c * 4);
    tile[r][c * 4 + 0] = v.x; tile[r][c * 4 + 1] = v.y;
    tile[r][c * 4 + 2] = v.z; tile[r][c * 4 + 3] = v.w;
  }
  __syncthreads();
  float* dst = WTF + (size_t)j0 * 1536 + i0;
  for (int e = threadIdx.x; e < 64 * 16; e += 256) {
    int jr = e >> 4, c = e & 15;
    float4 o;
    o.x = tile[c * 4 + 0][jr]; o.y = tile[c * 4 + 1][jr];
    o.z = tile[c * 4 + 2][jr]; o.w = tile[c * 4 + 3][jr];
    *(float4*)(dst + (size_t)jr * 1536 + c * 4) = o;
  }
}

// ---------------------------------------------------------------------------
// Fallback exact simulator (only when ws too small for fast path)
// ---------------------------------------------------------------------------
__global__ __launch_bounds__(256) void k_exact(const float* __restrict__ X, const float* __restrict__ W,
                                               const float* __restrict__ WTF, int use_wt,
                                               float* __restrict__ out) {
  const int b = blockIdx.x, tid = threadIdx.x;
  const int wv = tid >> 6, lane = tid & 63;
  float st[6], rf[6];
#pragma unroll
  for (int r = 0; r < 6; ++r) { st[r] = 0.f; rf[r] = 0.f; }
  __shared__ unsigned int mask[64];
  for (int w = tid; w < 64; w += 256) mask[w] = 0u;
  __syncthreads();
  for (int t = 0; t < 512; ++t) {
    {
      float x = X[((size_t)b * 512 + tid) * 512 + t];
      unsigned long long bl = __ballot(x > 0.5f);
      if (lane == 0) { mask[2 * wv] = (unsigned int)bl; mask[2 * wv + 1] = (unsigned int)(bl >> 32); }
      x = X[((size_t)b * 512 + 256 + tid) * 512 + t];
      bl = __ballot(x > 0.5f);
      if (lane == 0) { mask[8 + 2 * wv] = (unsigned int)bl; mask[9 + 2 * wv] = (unsigned int)(bl >> 32); }
    }
    __syncthreads();
    float add[6] = {0.f, 0.f, 0.f, 0.f, 0.f, 0.f};
    for (int wd = 0; wd < 64; ++wd) {
      unsigned int m = mask[wd];
      while (m) {
        int bitp = __ffs(m) - 1;
        m &= m - 1;
        int j = wd * 32 + bitp;
        if (use_wt) {
          const float* row = WTF + (size_t)j * 1536;
#pragma unroll
          for (int r = 0; r < 6; ++r) add[r] += row[tid + 256 * r];
        } else {
#pragma unroll
          for (int r = 0; r < 6; ++r) add[r] += W[(size_t)(512 + tid + 256 * r) * 2048 + j];
        }
      }
    }
    bool sp[6];
#pragma unroll
    for (int r = 0; r < 6; ++r) {
      float a = fmaf(st[r], KOEFF, add[r]);
      if (rf[r] > 0.f) a = 0.f;
      sp[r] = a >= 1.0f;
      rf[r] -= 1.f;
      if (sp[r]) rf[r] = 2.f;
      if (a < -1.f) a = -1.f;
      st[r] = a;
      int gi = 512 + tid + 256 * r;
      if (gi >= 1792) out[((size_t)b * 256 + (gi - 1792)) * 512 + t] = sp[r] ? 1.f : 0.f;
    }
    __syncthreads();
#pragma unroll
    for (int r = 0; r < 6; ++r) {
      unsigned long long bl = __ballot(sp[r]);
      if (lane == 0) {
        mask[16 + 8 * r + 2 * wv] = (unsigned int)bl;
        mask[17 + 8 * r + 2 * wv] = (unsigned int)(bl >> 32);
      }
    }
    __syncthreads();
  }
}

// ---------------------------------------------------------------------------
extern "C" void kernel_launch(void* const* d_in, const int* in_sizes, int n_in,
                              void* d_out, int out_size, void* d_ws, size_t ws_size,
                              hipStream_t stream) {
  const float* X = (const float*)d_in[0];   // [64][512][512]
  const float* W = (const float*)d_in[1];   // [2048][2048]
  float* out = (float*)d_out;               // [64][256][512]
  char* ws = (char*)d_ws;

  const size_t SZ_XT  = 64ull * 512 * 512 * 2;     //  33,554,432
  const size_t SZ_WH  = 1536ull * 512 * 2;         //   1,572,864
  const size_t SZ_WT2 = 1536ull * 1536 * 4;        //   9,437,184
  const size_t SZ_U   = 64ull * 512 * 1536 * 2;    // 100,663,296 (bf16)
  const size_t SZ_P   = 64ull * 8 * 1536 * 4;      //   3,145,728
  const size_t SZ_FL  = 256;                       // 64 int flags
  const size_t NEED_FULL = SZ_XT + SZ_WH + SZ_WT2 + SZ_U + SZ_P + SZ_FL;
  const size_t NEED_MID  = 2048ull * 1536 * 4;

  if (ws_size >= NEED_FULL) {
    u16*   XT  = (u16*)ws;
    u16*   Whi = (u16*)(ws + SZ_XT);
    float* WT2 = (float*)(ws + SZ_XT + SZ_WH);
    u16*   U   = (u16*)(ws + SZ_XT + SZ_WH + SZ_WT2);
    float* P   = (float*)(ws + SZ_XT + SZ_WH + SZ_WT2 + SZ_U);
    int*   FL  = (int*)(ws + SZ_XT + SZ_WH + SZ_WT2 + SZ_U + SZ_P);
    k_xt<<<dim3(8, 8, 64), 256, 0, stream>>>(X, XT);
    k_wcvt<<<3072, 256, 0, stream>>>(W, Whi, FL);
    k_wt2<<<dim3(24, 24), 256, 0, stream>>>(W, WT2);
    k_gemm<<<dim3(48, 64), 256, 0, stream>>>(Whi, XT, U);
    k_part<<<dim3(3, 8, 64), 256, 0, stream>>>(U, P);
    k_chunk<<<dim3(3, 8, 64), 256, 0, stream>>>(U, P, out, FL);
    k_fix<<<64, 768, 0, stream>>>(U, WT2, FL, out);
  } else if (ws_size >= NEED_MID) {
    float* WTF = (float*)ws;
    k_wtf<<<dim3(24, 32), 256, 0, stream>>>(W, WTF);
    k_exact<<<64, 256, 0, stream>>>(X, W, WTF, 1, out);
  } else {
    k_exact<<<64, 256, 0, stream>>>(X, W, nullptr, 0, out);
  }
}

// Round 6
// 237.392 us; speedup vs baseline: 4.2649x; 1.0615x over previous
//
#include <hip/hip_runtime.h>

// LIF constants (match reference)
#define KOEFF 0.951229424500714f
#define K64   0.040762204f            // KOEFF^64 = exp(-3.2)
#define LOG2K (-0.07213475204444817f) // log2(KOEFF) = -0.05/ln(2), exact: K=e^-0.05

typedef unsigned short u16;
typedef __attribute__((ext_vector_type(8))) short short8;   // 8 bf16 = 4 VGPRs (MFMA A/B frag)
typedef __attribute__((ext_vector_type(4))) float f32x4;    // MFMA C/D frag

__device__ __forceinline__ u16 f2bf(float f) {
  unsigned int v = __float_as_uint(f);
  unsigned int r = (v + 0x7FFFu + ((v >> 16) & 1u)) >> 16;
  return (u16)r;
}
__device__ __forceinline__ float bf2f(u16 u) {
  return __uint_as_float(((unsigned int)u) << 16);
}

// ---------------------------------------------------------------------------
// Kernel 1 (merged prep): blockIdx.x partitions three independent jobs:
//   [0,4096)      : X [64][512 j][512 t] fp32 -> XT16 [64][512 t][512 j] bf16
//   [4096,7168)   : W rows 512..2047 cols 0..511 -> bf16 Whi[1536][512]; zero flags
//   [7168,7744)   : WT2[j'][i'] = W[512+i'][512+j'] (recurrent block, transposed)
// ---------------------------------------------------------------------------
__global__ __launch_bounds__(256) void k_prep(const float* __restrict__ X, const float* __restrict__ W,
                                              u16* __restrict__ XT, u16* __restrict__ Whi,
                                              float* __restrict__ WT2, int* __restrict__ flags) {
  __shared__ float tile[64][65];
  const int blk = blockIdx.x;
  if (blk < 4096) {
    // --- X transpose+cvt ---
    const int b  = blk >> 6;
    const int r2 = blk & 63;
    const int j0 = (r2 & 7) * 64;
    const int t0 = (r2 >> 3) * 64;
    const float* src = X + ((size_t)b * 512 + j0) * 512 + t0;
    for (int e = threadIdx.x; e < 64 * 16; e += 256) {
      int r = e >> 4, c = e & 15;
      float4 v = *(const float4*)(src + (size_t)r * 512 + c * 4);
      tile[r][c * 4 + 0] = v.x; tile[r][c * 4 + 1] = v.y;
      tile[r][c * 4 + 2] = v.z; tile[r][c * 4 + 3] = v.w;
    }
    __syncthreads();
    u16* dst = XT + ((size_t)b * 512 + t0) * 512 + j0;
    for (int e = threadIdx.x; e < 64 * 16; e += 256) {
      int tr = e >> 4, c = e & 15;
      ushort4 o;
      o.x = f2bf(tile[c * 4 + 0][tr]); o.y = f2bf(tile[c * 4 + 1][tr]);
      o.z = f2bf(tile[c * 4 + 2][tr]); o.w = f2bf(tile[c * 4 + 3][tr]);
      *(ushort4*)(dst + (size_t)tr * 512 + c * 4) = o;
    }
  } else if (blk < 7168) {
    // --- W -> bf16 (feed-forward block) + flag zeroing ---
    if (blk == 4096 && threadIdx.x < 64) flags[threadIdx.x] = 0;
    int p = (blk - 4096) * 256 + threadIdx.x;   // exactly covers 1536*512
    int i = p >> 9, j = p & 511;
    Whi[p] = f2bf(W[(size_t)(512 + i) * 2048 + j]);
  } else {
    // --- recurrent-block transpose ---
    const int bx = blk - 7168;            // 0..575
    const int i0 = (bx / 24) * 64;
    const int j0 = (bx % 24) * 64;
    const float* src = W + (size_t)(512 + i0) * 2048 + 512 + j0;
    for (int e = threadIdx.x; e < 64 * 16; e += 256) {
      int r = e >> 4, c = e & 15;
      float4 v = *(const float4*)(src + (size_t)r * 2048 + c * 4);
      tile[r][c * 4 + 0] = v.x; tile[r][c * 4 + 1] = v.y;
      tile[r][c * 4 + 2] = v.z; tile[r][c * 4 + 3] = v.w;
    }
    __syncthreads();
    float* dst = WT2 + (size_t)j0 * 1536 + i0;
    for (int e = threadIdx.x; e < 64 * 16; e += 256) {
      int jr = e >> 4, c = e & 15;
      float4 o;
      o.x = tile[c * 4 + 0][jr]; o.y = tile[c * 4 + 1][jr];
      o.z = tile[c * 4 + 2][jr]; o.w = tile[c * 4 + 3][jr];
      *(float4*)(dst + (size_t)jr * 1536 + c * 4) = o;
    }
  }
}

// ---------------------------------------------------------------------------
// Kernel 2: U16[b][t][i'] = bf16( sum_j Whi[i'][j] * XT16[b][t][j] )
// 128x128 tile, BK=64, 4 waves each 64x64, T2 XOR-swizzle (pre-swizzled global
// source, rule #21). Epilogue ALSO computes the per-chunk weighted partials
// P[b][c][i'] = sum_{j=0..63} K^{63-j} U[b][c*64+j][i'] in-register
// (each wave's 64x64 sub-tile is exactly one chunk x 64 neurons; width-16
// shfl_xor reduces over the t-lanes; no atomics needed).
// ---------------------------------------------------------------------------
__global__ __launch_bounds__(256) void k_gemm(const u16* __restrict__ A,
                                              const u16* __restrict__ Bx, u16* __restrict__ U,
                                              float* __restrict__ P) {
  __shared__ u16 lA[128 * 64];
  __shared__ u16 lB[128 * 64];
  const int b    = blockIdx.y;
  const int mt   = blockIdx.x >> 2;
  const int nt   = blockIdx.x & 3;
  const int tid  = threadIdx.x;
  const int wv   = tid >> 6;
  const int lane = tid & 63;
  const int wr   = wv >> 1, wc = wv & 1;

  f32x4 acc[4][4];
#pragma unroll
  for (int mi = 0; mi < 4; ++mi)
#pragma unroll
    for (int ni = 0; ni < 4; ++ni) acc[mi][ni] = (f32x4)0.0f;

  const u16* gA = A + (size_t)mt * 128 * 512;
  const u16* gB = Bx + ((size_t)b * 512 + nt * 128) * 512;

  for (int k0 = 0; k0 < 512; k0 += 64) {
#pragma unroll
    for (int it = 0; it < 4; ++it) {
      int byteoff = wv * 4096 + it * 1024 + lane * 16;
      int row   = byteoff >> 7;          // 128B per LDS row (64 bf16 of k)
      int chunk = (byteoff >> 4) & 7;    // 16B chunk within row
      int ksub  = (chunk ^ (row & 7)) * 8;   // pre-swizzled global source
      int ldsoff = wv * 2048 + it * 512;     // u16 elems, wave-uniform (linear dest)
      __builtin_amdgcn_global_load_lds(
          (const __attribute__((address_space(1))) void*)(gA + (size_t)row * 512 + k0 + ksub),
          (__attribute__((address_space(3))) void*)(lA + ldsoff), 16, 0, 0);
      __builtin_amdgcn_global_load_lds(
          (const __attribute__((address_space(1))) void*)(gB + (size_t)row * 512 + k0 + ksub),
          (__attribute__((address_space(3))) void*)(lB + ldsoff), 16, 0, 0);
    }
    __syncthreads();
#pragma unroll
    for (int kk = 0; kk < 2; ++kk) {
      short8 ah[4], bb[4];
      const int kc = kk * 4 + (lane >> 4);   // chunk index 0..7
      const int sw = lane & 7;               // == (row&7) for our rows
#pragma unroll
      for (int mi = 0; mi < 4; ++mi) {
        int m = wr * 64 + mi * 16 + (lane & 15);
        ah[mi] = *(const short8*)&lA[m * 64 + ((kc ^ sw) << 3)];
      }
#pragma unroll
      for (int ni = 0; ni < 4; ++ni) {
        int n = wc * 64 + ni * 16 + (lane & 15);
        bb[ni] = *(const short8*)&lB[n * 64 + ((kc ^ sw) << 3)];
      }
#pragma unroll
      for (int mi = 0; mi < 4; ++mi)
#pragma unroll
        for (int ni = 0; ni < 4; ++ni)
          acc[mi][ni] = __builtin_amdgcn_mfma_f32_16x16x32_bf16(ah[mi], bb[ni], acc[mi][ni], 0, 0, 0);
    }
    __syncthreads();
  }
  // --- epilogue 1: U tile store (bf16). D layout: col=lane&15 (t), row=(lane>>4)*4+q (i)
#pragma unroll
  for (int mi = 0; mi < 4; ++mi) {
    int ib = mt * 128 + wr * 64 + mi * 16 + ((lane >> 4) << 2);
#pragma unroll
    for (int ni = 0; ni < 4; ++ni) {
      int t = nt * 128 + wc * 64 + ni * 16 + (lane & 15);
      f32x4 v = acc[mi][ni];
      ushort4 o;
      o.x = f2bf(v.x); o.y = f2bf(v.y); o.z = f2bf(v.z); o.w = f2bf(v.w);
      *(ushort4*)(U + ((size_t)b * 512 + t) * 1536 + ib) = o;
    }
  }
  // --- epilogue 2: fused chunk partials. This wave's t-range = chunk c.
  {
    const int tl = lane & 15;
    const int c  = nt * 2 + wc;
    float pv[4][4];
#pragma unroll
    for (int mi = 0; mi < 4; ++mi)
#pragma unroll
      for (int q = 0; q < 4; ++q) pv[mi][q] = 0.f;
#pragma unroll
    for (int ni = 0; ni < 4; ++ni) {
      float w = exp2f(LOG2K * (float)(63 - ni * 16 - tl));  // K^{63 - t_local}
#pragma unroll
      for (int mi = 0; mi < 4; ++mi) {
        f32x4 a = acc[mi][ni];
        pv[mi][0] = fmaf(w, a.x, pv[mi][0]);
        pv[mi][1] = fmaf(w, a.y, pv[mi][1]);
        pv[mi][2] = fmaf(w, a.z, pv[mi][2]);
        pv[mi][3] = fmaf(w, a.w, pv[mi][3]);
      }
    }
#pragma unroll
    for (int off = 1; off < 16; off <<= 1)
#pragma unroll
      for (int mi = 0; mi < 4; ++mi)
#pragma unroll
        for (int q = 0; q < 4; ++q)
          pv[mi][q] += __shfl_xor(pv[mi][q], off, 16);
    if (tl == 0) {
      int ib = mt * 128 + wr * 64 + ((lane >> 4) << 2);
      float* pb = P + ((size_t)b * 8 + c) * 1536 + ib;
#pragma unroll
      for (int mi = 0; mi < 4; ++mi)
#pragma unroll
        for (int q = 0; q < 4; ++q) pb[mi * 16 + q] = pv[mi][q];
    }
  }
}

// ---------------------------------------------------------------------------
// Kernel 3: chunk walk over bf16 U, 2 neurons/thread. Reconstruct
// chunk-start state from P, walk 64 steps linearly, emit spikes for
// i>=1280, flag any violation (spike or clamp) -> batch redone by k_fix.
// ---------------------------------------------------------------------------
__global__ __launch_bounds__(256) void k_chunk(const u16* __restrict__ U, const float* __restrict__ P,
                                               float* __restrict__ out, int* __restrict__ flags) {
  const int g = blockIdx.x * 256 + threadIdx.x;   // 0..767
  const int i = g * 2;
  const int c = blockIdx.y, b = blockIdx.z;
  float s0 = 0.f, s1 = 0.f;
  const float* pp = P + (size_t)b * 8 * 1536 + i;
  for (int d = 0; d < c; ++d) {
    float2 pv = *(const float2*)(pp + (size_t)d * 1536);
    s0 = fmaf(s0, K64, pv.x);
    s1 = fmaf(s1, K64, pv.y);
  }
  const u16* up = U + ((size_t)b * 512 + c * 64) * 1536 + i;
  const bool wr = (i >= 1280);
  float* op = out + ((size_t)b * 256 + (i - 1280)) * 512 + c * 64;  // valid only if wr
  bool viol = false;
  unsigned int buf[8];
#pragma unroll
  for (int j = 0; j < 8; ++j) buf[j] = *(const unsigned int*)(up + (size_t)j * 1536);
  for (int t0 = 0; t0 < 64; t0 += 8) {
    float sp0[8], sp1[8];
#pragma unroll
    for (int j = 0; j < 8; ++j) {
      unsigned int u = buf[j];
      if (t0 + 8 < 64) buf[j] = *(const unsigned int*)(up + (size_t)(t0 + 8 + j) * 1536);
      s0 = fmaf(s0, KOEFF, bf2f((u16)(u & 0xffffu)));
      s1 = fmaf(s1, KOEFF, bf2f((u16)(u >> 16)));
      bool a = (s0 >= 1.0f), bsp = (s1 >= 1.0f);
      viol = viol || a || bsp || (s0 < -1.0f) || (s1 < -1.0f);
      sp0[j] = a ? 1.f : 0.f;
      sp1[j] = bsp ? 1.f : 0.f;
    }
    if (wr) {
      *(float4*)(op + t0)           = make_float4(sp0[0], sp0[1], sp0[2], sp0[3]);
      *(float4*)(op + t0 + 4)       = make_float4(sp0[4], sp0[5], sp0[6], sp0[7]);
      *(float4*)(op + 512 + t0)     = make_float4(sp1[0], sp1[1], sp1[2], sp1[3]);
      *(float4*)(op + 512 + t0 + 4) = make_float4(sp1[4], sp1[5], sp1[6], sp1[7]);
    }
  }
  if (viol) atomicOr(&flags[b], 1);
}

// ---------------------------------------------------------------------------
// Kernel 4: exact sequential scan (bf16 U), gated per batch on spike flag.
// Expected: immediate exit for all batches. Correctness backstop.
// ---------------------------------------------------------------------------
__global__ __launch_bounds__(768) void k_fix(const u16* __restrict__ U, const float* __restrict__ WT2,
                                             const int* __restrict__ flags, float* __restrict__ out) {
  const int b = blockIdx.x;
  if (flags[b] == 0) return;   // uniform per block
  const int tid = threadIdx.x;
  const int wv = tid >> 6, lane = tid & 63;
  __shared__ unsigned long long spk[24];
  for (int w = tid; w < 24; w += 768) spk[w] = 0ULL;
  __syncthreads();
  float s0 = 0.f, s1 = 0.f, r0 = 0.f, r1 = 0.f;
  const int i0 = 2 * tid;
  const u16* ub = U + (size_t)b * 512 * 1536 + i0;
  unsigned int u = *(const unsigned int*)ub;
  for (int t = 0; t < 512; ++t) {
    unsigned int unext = u;
    if (t < 511) unext = *(const unsigned int*)(ub + (size_t)(t + 1) * 1536);
    float a0 = fmaf(s0, KOEFF, bf2f((u16)(u & 0xffffu)));
    float a1 = fmaf(s1, KOEFF, bf2f((u16)(u >> 16)));
    for (int wd = 0; wd < 24; ++wd) {
      unsigned long long m = spk[wd];
      while (m) {
        int bit = __ffsll(m) - 1;
        m &= m - 1;
        int jp = ((wd >> 1) << 7) + (bit << 1) + (wd & 1);
        float2 rv = *(const float2*)(WT2 + (size_t)jp * 1536 + i0);
        a0 += rv.x; a1 += rv.y;
      }
    }
    if (r0 > 0.f) a0 = 0.f;
    if (r1 > 0.f) a1 = 0.f;
    bool sp0 = a0 >= 1.0f, sp1 = a1 >= 1.0f;
    r0 -= 1.f; r1 -= 1.f;
    if (sp0) r0 = 2.f;
    if (sp1) r1 = 2.f;
    if (a0 < -1.f) a0 = -1.f;
    if (a1 < -1.f) a1 = -1.f;
    s0 = a0; s1 = a1;
    if (i0 >= 1280) {
      float* o = out + ((size_t)b * 256 + (i0 - 1280)) * 512 + t;
      o[0]   = sp0 ? 1.f : 0.f;
      o[512] = sp1 ? 1.f : 0.f;
    }
    __syncthreads();
    unsigned long long b0 = __ballot(sp0);
    unsigned long long b1 = __ballot(sp1);
    if (lane == 0) { spk[2 * wv] = b0; spk[2 * wv + 1] = b1; }
    __syncthreads();
    u = unext;
  }
}

// ---------------------------------------------------------------------------
// Fallback: WTF[j][i'] = W[512+i'][j] for all j in [0,2048)
// ---------------------------------------------------------------------------
__global__ __launch_bounds__(256) void k_wtf(const float* __restrict__ W, float* __restrict__ WTF) {
  __shared__ float tile[64][65];
  const int i0 = blockIdx.x * 64;
  const int j0 = blockIdx.y * 64;
  const float* src = W + (size_t)(512 + i0) * 2048 + j0;
  for (int e = threadIdx.x; e < 64 * 16; e += 256) {
    int r = e >> 4, c = e & 15;
    float4 v = *(const float4*)(src + (size_t)r * 2048 + c * 4);
    tile[r][c * 4 + 0] = v.x; tile[r][c * 4 + 1] = v.y;
    tile[r][c * 4 + 2] = v.z; tile[r][c * 4 + 3] = v.w;
  }
  __syncthreads();
  float* dst = WTF + (size_t)j0 * 1536 + i0;
  for (int e = threadIdx.x; e < 64 * 16; e += 256) {
    int jr = e >> 4, c = e & 15;
    float4 o;
    o.x = tile[c * 4 + 0][jr]; o.y = tile[c * 4 + 1][jr];
    o.z = tile[c * 4 + 2][jr]; o.w = tile[c * 4 + 3][jr];
    *(float4*)(dst + (size_t)jr * 1536 + c * 4) = o;
  }
}

// ---------------------------------------------------------------------------
// Fallback exact simulator (only when ws too small for fast path)
// ---------------------------------------------------------------------------
__global__ __launch_bounds__(256) void k_exact(const float* __restrict__ X, const float* __restrict__ W,
                                               const float* __restrict__ WTF, int use_wt,
                                               float* __restrict__ out) {
  const int b = blockIdx.x, tid = threadIdx.x;
  const int wv = tid >> 6, lane = tid & 63;
  float st[6], rf[6];
#pragma unroll
  for (int r = 0; r < 6; ++r) { st[r] = 0.f; rf[r] = 0.f; }
  __shared__ unsigned int mask[64];
  for (int w = tid; w < 64; w += 256) mask[w] = 0u;
  __syncthreads();
  for (int t = 0; t < 512; ++t) {
    {
      float x = X[((size_t)b * 512 + tid) * 512 + t];
      unsigned long long bl = __ballot(x > 0.5f);
      if (lane == 0) { mask[2 * wv] = (unsigned int)bl; mask[2 * wv + 1] = (unsigned int)(bl >> 32); }
      x = X[((size_t)b * 512 + 256 + tid) * 512 + t];
      bl = __ballot(x > 0.5f);
      if (lane == 0) { mask[8 + 2 * wv] = (unsigned int)bl; mask[9 + 2 * wv] = (unsigned int)(bl >> 32); }
    }
    __syncthreads();
    float add[6] = {0.f, 0.f, 0.f, 0.f, 0.f, 0.f};
    for (int wd = 0; wd < 64; ++wd) {
      unsigned int m = mask[wd];
      while (m) {
        int bitp = __ffs(m) - 1;
        m &= m - 1;
        int j = wd * 32 + bitp;
        if (use_wt) {
          const float* row = WTF + (size_t)j * 1536;
#pragma unroll
          for (int r = 0; r < 6; ++r) add[r] += row[tid + 256 * r];
        } else {
#pragma unroll
          for (int r = 0; r < 6; ++r) add[r] += W[(size_t)(512 + tid + 256 * r) * 2048 + j];
        }
      }
    }
    bool sp[6];
#pragma unroll
    for (int r = 0; r < 6; ++r) {
      float a = fmaf(st[r], KOEFF, add[r]);
      if (rf[r] > 0.f) a = 0.f;
      sp[r] = a >= 1.0f;
      rf[r] -= 1.f;
      if (sp[r]) rf[r] = 2.f;
      if (a < -1.f) a = -1.f;
      st[r] = a;
      int gi = 512 + tid + 256 * r;
      if (gi >= 1792) out[((size_t)b * 256 + (gi - 1792)) * 512 + t] = sp[r] ? 1.f : 0.f;
    }
    __syncthreads();
#pragma unroll
    for (int r = 0; r < 6; ++r) {
      unsigned long long bl = __ballot(sp[r]);
      if (lane == 0) {
        mask[16 + 8 * r + 2 * wv] = (unsigned int)bl;
        mask[17 + 8 * r + 2 * wv] = (unsigned int)(bl >> 32);
      }
    }
    __syncthreads();
  }
}

// ---------------------------------------------------------------------------
extern "C" void kernel_launch(void* const* d_in, const int* in_sizes, int n_in,
                              void* d_out, int out_size, void* d_ws, size_t ws_size,
                              hipStream_t stream) {
  const float* X = (const float*)d_in[0];   // [64][512][512]
  const float* W = (const float*)d_in[1];   // [2048][2048]
  float* out = (float*)d_out;               // [64][256][512]
  char* ws = (char*)d_ws;

  const size_t SZ_XT  = 64ull * 512 * 512 * 2;     //  33,554,432
  const size_t SZ_WH  = 1536ull * 512 * 2;         //   1,572,864
  const size_t SZ_WT2 = 1536ull * 1536 * 4;        //   9,437,184
  const size_t SZ_U   = 64ull * 512 * 1536 * 2;    // 100,663,296 (bf16)
  const size_t SZ_P   = 64ull * 8 * 1536 * 4;      //   3,145,728
  const size_t SZ_FL  = 256;                       // 64 int flags
  const size_t NEED_FULL = SZ_XT + SZ_WH + SZ_WT2 + SZ_U + SZ_P + SZ_FL;
  const size_t NEED_MID  = 2048ull * 1536 * 4;

  if (ws_size >= NEED_FULL) {
    u16*   XT  = (u16*)ws;
    u16*   Whi = (u16*)(ws + SZ_XT);
    float* WT2 = (float*)(ws + SZ_XT + SZ_WH);
    u16*   U   = (u16*)(ws + SZ_XT + SZ_WH + SZ_WT2);
    float* P   = (float*)(ws + SZ_XT + SZ_WH + SZ_WT2 + SZ_U);
    int*   FL  = (int*)(ws + SZ_XT + SZ_WH + SZ_WT2 + SZ_U + SZ_P);
    k_prep<<<7744, 256, 0, stream>>>(X, W, XT, Whi, WT2, FL);
    k_gemm<<<dim3(48, 64), 256, 0, stream>>>(Whi, XT, U, P);
    k_chunk<<<dim3(3, 8, 64), 256, 0, stream>>>(U, P, out, FL);
    k_fix<<<64, 768, 0, stream>>>(U, WT2, FL, out);
  } else if (ws_size >= NEED_MID) {
    float* WTF = (float*)ws;
    k_wtf<<<dim3(24, 32), 256, 0, stream>>>(W, WTF);
    k_exact<<<64, 256, 0, stream>>>(X, W, WTF, 1, out);
  } else {
    k_exact<<<64, 256, 0, stream>>>(X, W, nullptr, 0, out);
  }
}